// Round 8
// baseline (35492.963 us; speedup 1.0000x reference)
//
#include <hip/hip_runtime.h>
#include <hip/hip_bf16.h>

// Zero-sync decoder: 128 independent blocks x 512 thr; block owns 16 batch rows
// for ALL 256 steps. No grid barriers, no fences (R3-R7 post-mortems: every
// device-scope sync forces an L2 invalidate whose refill costs ~70us/step).
// All per-row state lives in LDS/regs; weights stream from XCD-local L2:
//   per step per block: Wbig 2.36MB + Wsmall 160KB from L2 (L2-resident,
//   per-XCD read set ~2.6MB < 4MB).
// Step layout (block-local, 4 __syncthreads per step):
//   preload A-frags(xh) -> S1 -> gates GEMM (M=16,N=2048,K=576, B reg-ring) +
//   fused LSTM cell (shfl gate gather, c in LDS, h2 in-place to xh) -> S2 ->
//   head(logits t) + Uh-GEMM -> S3 -> attention (Ws recompute via MFMA from
//   LDS parts, score/softmax/ctx -> xh cols 512:556) -> S4.

typedef __attribute__((ext_vector_type(8))) short short8;
typedef __attribute__((ext_vector_type(4))) float floatx4;

#define DEV static __device__ __forceinline__
#define C2LE 2.885390082f    // 2*log2(e)
#define LOG2E 1.4426950409f
#define LN2 0.6931471806f

DEV unsigned short f2bf(float f) {
    unsigned int u = __float_as_uint(f);
    unsigned int r = (u + 0x7FFFu + ((u >> 16) & 1u)) >> 16;
    return (unsigned short)r;
}
DEV float bf2f(unsigned short u) { return __uint_as_float(((unsigned int)u) << 16); }
DEV float rcp_f(float x) { float r; asm("v_rcp_f32 %0, %1" : "=v"(r) : "v"(x)); return r; }
DEV float tanh_f(float x) { return 1.f - 2.f * rcp_f(1.f + exp2f(x * C2LE)); }
DEV float sigm(float x) { return rcp_f(1.f + exp2f(-x * LOG2E)); }

// ---------------- workspace layout (bytes) ----------------
#define OFF_H0     ((size_t)0)          // bf16 [2048][512]
#define OFF_C0     ((size_t)2097152)    // f32  [2048][512]
#define OFF_PARTS  ((size_t)6291456)    // bf16 [2048][64][32]
#define OFF_WBIG   ((size_t)14680064)   // bf16 [2048][576], perm row p=4j+g <- orig g*512+j
#define OFF_WSMALL ((size_t)17039360)   // bf16 [160][512]: Uw(128), betaw(32)
#define OFF_WW2    ((size_t)17203200)   // bf16 [128][32] = C2LE*Ww
#define OFF_BIAS   ((size_t)17211392)   // f32  [2048] b_ih+b_hh (orig order)
#define OFF_AVG    ((size_t)17219584)   // f32  [2048][64]

__global__ void k_avg(const float* __restrict__ img, float* __restrict__ avg) {
    int idx = blockIdx.x * 256 + threadIdx.x;
    int b = idx >> 6, p = idx & 63;
    const float* base = img + (size_t)b * 2048 + p;
    float s = 0.f;
#pragma unroll
    for (int k = 0; k < 32; ++k) s += base[k * 64];
    avg[idx] = s * (1.f / 32.f);
}

__global__ void k_prep(const float* __restrict__ Whh, const float* __restrict__ Wih,
                       const float* __restrict__ Uw, const float* __restrict__ betaw,
                       const float* __restrict__ Ww, const float* __restrict__ bih,
                       const float* __restrict__ bhh,
                       unsigned short* __restrict__ Wbig, unsigned short* __restrict__ Wsmall,
                       unsigned short* __restrict__ Ww2, float* __restrict__ bias_cat) {
    int p = blockIdx.x, tid = threadIdx.x;
    int g = p & 3, j = p >> 2, orig = g * 512 + j;
    for (int k = tid; k < 576; k += 256) {
        float v = 0.f;
        if (k < 512) v = Whh[(size_t)orig * 512 + k];
        else if (k < 556) v = Wih[(size_t)orig * 44 + (k - 512)];
        Wbig[(size_t)p * 576 + k] = f2bf(v);
    }
    if (p < 160) {
        for (int k = tid; k < 512; k += 256) {
            float v = (p < 128) ? Uw[(size_t)p * 512 + k] : betaw[(size_t)(p - 128) * 512 + k];
            Wsmall[(size_t)p * 512 + k] = f2bf(v);
        }
    }
    if (p < 128 && tid < 32) Ww2[p * 32 + tid] = f2bf(C2LE * Ww[p * 32 + tid]);
    if (tid == 0) bias_cat[orig] = bih[orig] + bhh[orig];
}

__global__ __launch_bounds__(512) void k_h0c0(const float* __restrict__ avg,
                                              const float* __restrict__ ihw, const float* __restrict__ ihb,
                                              const float* __restrict__ icw, const float* __restrict__ icb,
                                              unsigned short* __restrict__ h0, float* __restrict__ c0) {
    __shared__ float avg_s[8][64];
    int b0 = blockIdx.x * 8, tid = threadIdx.x;
    for (int i = tid; i < 8 * 64; i += 512) avg_s[i >> 6][i & 63] = avg[b0 * 64 + i];
    __syncthreads();
    int j = tid;
    float w0[64];
#pragma unroll
    for (int p4 = 0; p4 < 16; ++p4) {
        float4 v = ((const float4*)(ihw + j * 64))[p4];
        w0[p4 * 4 + 0] = v.x; w0[p4 * 4 + 1] = v.y; w0[p4 * 4 + 2] = v.z; w0[p4 * 4 + 3] = v.w;
    }
    float bh = ihb[j];
#pragma unroll
    for (int bb = 0; bb < 8; ++bb) {
        float s = bh;
#pragma unroll
        for (int p = 0; p < 64; ++p) s += w0[p] * avg_s[bb][p];
        h0[(size_t)(b0 + bb) * 512 + j] = f2bf(tanh_f(s));
    }
#pragma unroll
    for (int p4 = 0; p4 < 16; ++p4) {
        float4 v = ((const float4*)(icw + j * 64))[p4];
        w0[p4 * 4 + 0] = v.x; w0[p4 * 4 + 1] = v.y; w0[p4 * 4 + 2] = v.z; w0[p4 * 4 + 3] = v.w;
    }
    float bc = icb[j];
#pragma unroll
    for (int bb = 0; bb < 8; ++bb) {
        float s = bc;
#pragma unroll
        for (int p = 0; p < 64; ++p) s += w0[p] * avg_s[bb][p];
        c0[(size_t)(b0 + bb) * 512 + j] = tanh_f(s);
    }
}

// parts_bf[b][p][k] = bf16(img[b][k][p])
__global__ __launch_bounds__(256) void k_parts(const float* __restrict__ img,
                                               unsigned short* __restrict__ parts_bf) {
    __shared__ float pl[64][33];
    int b = blockIdx.x, tid = threadIdx.x;
    const float* ib = img + (size_t)b * 2048;
    for (int i = tid; i < 2048; i += 256) pl[i & 63][i >> 6] = ib[i];
    __syncthreads();
    for (int i = tid; i < 2048; i += 256)
        parts_bf[(size_t)b * 2048 + i] = f2bf(pl[i >> 5][i & 31]);
}

__global__ __launch_bounds__(512, 2) void k_scan(
    const unsigned short* __restrict__ h0, const float* __restrict__ c0,
    const unsigned short* __restrict__ parts_bf,
    const unsigned short* __restrict__ Wsmall, const unsigned short* __restrict__ Wbig,
    const unsigned short* __restrict__ Ww2, const float* __restrict__ bias_cat,
    const float* __restrict__ Ub, const float* __restrict__ betab, const float* __restrict__ Wb,
    const float* __restrict__ vw,
    const float* __restrict__ label, const float* __restrict__ ow, const float* __restrict__ ob,
    float* __restrict__ out_alpha, float* __restrict__ out_logits)
{
    __shared__ unsigned short xh[16][584];       // 18.7KB  h|x|ctx|zero-pad
    __shared__ unsigned short parts_l[16][2304]; // 73.7KB  [p][36] padded (bank-spread)
    __shared__ float c_l[16][516];               // 33KB    padded
    __shared__ float uh_l[16][160];              // 10.2KB
    __shared__ float al_l[16][64];               // 4KB
    __shared__ float bias_l[2048];               // 8KB
    __shared__ unsigned short ow_l[12][512];     // 12.3KB
    __shared__ float vw2_l[128];
    __shared__ float obl[12];

    const int tid = threadIdx.x, w = tid >> 6, lane = tid & 63;
    const int b0 = blockIdx.x * 16;

    // ---- prologue staging (one-time) ----
    for (int i = tid; i < 2048; i += 512) bias_l[i] = bias_cat[i];
    for (int i = tid; i < 12 * 512; i += 512) ow_l[i >> 9][i & 511] = f2bf(ow[i]);
    if (tid < 128) vw2_l[tid] = -2.f * vw[tid];
    if (tid < 12) obl[tid] = ob[tid];
    for (int i = tid; i < 16 * 64; i += 512) {
        int row = i >> 6, p = i & 63;
        const short8* src = (const short8*)(parts_bf + (size_t)(b0 + row) * 2048 + p * 32);
        short8* dst = (short8*)&parts_l[row][p * 36];
        dst[0] = src[0]; dst[1] = src[1]; dst[2] = src[2]; dst[3] = src[3];
    }
    for (int i = tid; i < 16 * 64; i += 512) {
        int row = i >> 6, c8 = (i & 63) * 8;
        *(short8*)&xh[row][c8] = *(const short8*)(h0 + (size_t)(b0 + row) * 512 + c8);
    }
    for (int i = tid; i < 16 * 72; i += 512) {
        int row = i / 72, cc = 512 + (i % 72);
        xh[row][cc] = 0;
    }
    for (int i = tid; i < 16 * 512; i += 512) {
        int row = i >> 9, j = i & 511;
        c_l[row][j] = c0[(size_t)(b0 + row) * 512 + j];
    }
    __syncthreads();
    float vwsum = 0.f;
#pragma unroll
    for (int d = 0; d < 128; ++d) vwsum += vw2_l[d];
    vwsum *= -0.5f;

    // ---- Uh GEMM: uh_l[16][160] = h @ Wsmall^T (+bias/scale) ----
    auto do_uh = [&]() {
        for (int nt = w; nt < 10; nt += 8) {
            const unsigned short* Bp = Wsmall + (size_t)(nt * 16 + (lane & 15)) * 512 + (lane >> 4) * 8;
            floatx4 u = {};
#pragma unroll
            for (int k0 = 0; k0 < 512; k0 += 32) {
                short8 a = *(const short8*)&xh[lane & 15][k0 + (lane >> 4) * 8];
                u = __builtin_amdgcn_mfma_f32_16x16x32_bf16(a, *(const short8*)(Bp + k0), u, 0, 0, 0);
            }
            int n = nt * 16 + (lane & 15), r0 = (lane >> 4) * 4;
            float addv = (n < 128) ? (Ub[n] + Wb[n]) : betab[n - 128];
            float scl = (n < 128) ? C2LE : 1.f;
#pragma unroll
            for (int r = 0; r < 4; ++r) uh_l[r0 + r][n] = (u[r] + addv) * scl;
        }
    };

    // ---- attention for step tt: alpha(tt), x_tt, ctx_tt -> xh cols 512:556 ----
    auto do_attn = [&](int tt) {
#pragma unroll
        for (int u = 0; u < 2; ++u) {
            int row = w * 2 + u, b = b0 + row;
            short8 pa[4];
#pragma unroll
            for (int mt = 0; mt < 4; ++mt)
                pa[mt] = *(const short8*)&parts_l[row][(mt * 16 + (lane & 15)) * 36 + (lane >> 4) * 8];
            float sc[4][4] = {};
#pragma unroll
            for (int nt = 0; nt < 8; ++nt) {
                short8 wwf = *(const short8*)(Ww2 + (size_t)(nt * 16 + (lane & 15)) * 32 + (lane >> 4) * 8);
                int d = nt * 16 + (lane & 15);
                float ud = uh_l[row][d];
                float v2 = vw2_l[d];
#pragma unroll
                for (int mt = 0; mt < 4; ++mt) {
                    floatx4 z = {};
                    floatx4 wsa = __builtin_amdgcn_mfma_f32_16x16x32_bf16(pa[mt], wwf, z, 0, 0, 0);
#pragma unroll
                    for (int r = 0; r < 4; ++r)
                        sc[mt][r] += v2 * rcp_f(1.f + exp2f(wsa[r] + ud));
                }
            }
            float mx = -1e30f;
#pragma unroll
            for (int mt = 0; mt < 4; ++mt)
#pragma unroll
                for (int r = 0; r < 4; ++r) {
                    float s = sc[mt][r];
                    s += __shfl_xor(s, 1); s += __shfl_xor(s, 2);
                    s += __shfl_xor(s, 4); s += __shfl_xor(s, 8);
                    s += vwsum;
                    sc[mt][r] = s;
                    mx = fmaxf(mx, s);
                }
            mx = fmaxf(mx, __shfl_xor(mx, 16));
            mx = fmaxf(mx, __shfl_xor(mx, 32));
            float ssum = 0.f;
            float av[4][4];
#pragma unroll
            for (int mt = 0; mt < 4; ++mt)
#pragma unroll
                for (int r = 0; r < 4; ++r) {
                    av[mt][r] = exp2f((sc[mt][r] - mx) * LOG2E);
                    ssum += av[mt][r];
                }
            ssum += __shfl_xor(ssum, 16);
            ssum += __shfl_xor(ssum, 32);
            float rs = rcp_f(ssum);
#pragma unroll
            for (int mt = 0; mt < 4; ++mt) {
                if ((lane & 15) == mt) {
                    float4 fv = make_float4(av[mt][0] * rs, av[mt][1] * rs, av[mt][2] * rs, av[mt][3] * rs);
                    int p0 = mt * 16 + (lane >> 4) * 4;
                    *(float4*)&out_alpha[((size_t)tt * 2048 + b) * 64 + p0] = fv;
                    *(float4*)&al_l[row][p0] = fv;
                }
            }
            int k = lane & 31, half = lane >> 5;
            float cp = 0.f;
#pragma unroll
            for (int p = 0; p < 32; ++p) {
                int pp = half * 32 + p;
                cp += al_l[row][pp] * bf2f(parts_l[row][pp * 36 + k]);
            }
            cp += __shfl_xor(cp, 32);
            if (half == 0) xh[row][524 + k] = f2bf(cp * sigm(uh_l[row][128 + k]));
            if (lane < 12) xh[row][512 + lane] = f2bf(label[((size_t)b * 256 + tt) * 12 + lane]);
        }
    };

    do_uh();
    __syncthreads();
    do_attn(0);
    __syncthreads();

    for (int t = 0; t < 256; ++t) {
        // ---- preload A-frags (regs) so cell can write xh in-place ----
        short8 a[18];
#pragma unroll
        for (int k = 0; k < 18; ++k)
            a[k] = *(const short8*)&xh[lane & 15][k * 32 + (lane >> 4) * 8];
        __syncthreads();   // S1

        // ---- gates GEMM (wave owns p in [w*256,w*256+256)) + fused cell ----
#pragma unroll
        for (int ng = 0; ng < 4; ++ng) {
            const unsigned short* bp = Wbig + (size_t)(w * 256 + ng * 64 + (lane & 15)) * 576 + (lane >> 4) * 8;
            short8 br[3][4];
            floatx4 acc[4] = {};
#pragma unroll
            for (int kk = 0; kk < 2; ++kk)
#pragma unroll
                for (int q = 0; q < 4; ++q)
                    br[kk][q] = *(const short8*)(bp + (size_t)q * 9216 + kk * 32);
#pragma unroll
            for (int k = 0; k < 18; ++k) {
                if (k < 16) {
#pragma unroll
                    for (int q = 0; q < 4; ++q)
                        br[(k + 2) % 3][q] = *(const short8*)(bp + (size_t)q * 9216 + (k + 2) * 32);
                }
#pragma unroll
                for (int q = 0; q < 4; ++q)
                    acc[q] = __builtin_amdgcn_mfma_f32_16x16x32_bf16(a[k], br[k % 3][q], acc[q], 0, 0, 0);
            }
            int base = (lane & 48) | (4 * (lane & 3));
            int jl = lane & 3;
#pragma unroll
            for (int q = 0; q < 4; ++q) {
                int j = w * 64 + (ng * 4 + q) * 4 + jl;
                float bi = bias_l[j], bfv = bias_l[512 + j], bg = bias_l[1024 + j], bo = bias_l[1536 + j];
#pragma unroll
                for (int r = 0; r < 4; ++r) {
                    float x = acc[q][r];
                    float g0 = __shfl(x, base + 0);
                    float g1 = __shfl(x, base + 1);
                    float g2 = __shfl(x, base + 2);
                    float g3 = __shfl(x, base + 3);
                    int row = (lane >> 4) * 4 + r;
                    float cold = c_l[row][j];
                    float c2 = sigm(g1 + bfv) * cold + sigm(g0 + bi) * tanh_f(g2 + bg);
                    float h2 = sigm(g3 + bo) * tanh_f(c2);
                    if (((lane >> 2) & 3) == 0) {
                        c_l[row][j] = c2;
                        xh[row][j] = f2bf(h2);
                    }
                }
            }
        }
        __syncthreads();   // S2: h(t+1) complete

        // ---- output head: logits[t] from h(t+1) ----
#pragma unroll
        for (int u = 0; u < 2; ++u) {
            int row = w * 2 + u, b = b0 + row;
            short8 hv = *(const short8*)&xh[row][lane * 8];
            float hf[8];
#pragma unroll
            for (int j = 0; j < 8; ++j) hf[j] = bf2f((unsigned short)hv[j]);
            float ov[12];
#pragma unroll
            for (int v = 0; v < 12; ++v) {
                short8 wv = *(const short8*)&ow_l[v][lane * 8];
                float p = 0.f;
#pragma unroll
                for (int j = 0; j < 8; ++j) p += hf[j] * bf2f((unsigned short)wv[j]);
#pragma unroll
                for (int o = 32; o; o >>= 1) p += __shfl_xor(p, o);
                ov[v] = p + obl[v];
            }
            float mx = ov[0];
#pragma unroll
            for (int v = 1; v < 12; ++v) mx = fmaxf(mx, ov[v]);
            float ss = 0.f;
#pragma unroll
            for (int v = 0; v < 12; ++v) ss += exp2f((ov[v] - mx) * LOG2E);
            float lse = mx + log2f(ss) * LN2;
#pragma unroll
            for (int v = 0; v < 12; ++v)
                if (lane == v) out_logits[((size_t)b * 256 + t) * 12 + v] = ov[v] - lse;
        }
        if (t < 255) do_uh();
        __syncthreads();   // S3: uh_l complete
        if (t < 255) do_attn(t + 1);
        __syncthreads();   // S4: xh x/ctx complete before next preload
    }
}

extern "C" void kernel_launch(void* const* d_in, const int* in_sizes, int n_in,
                              void* d_out, int out_size, void* d_ws, size_t ws_size,
                              hipStream_t stream) {
    const float* img   = (const float*)d_in[0];
    const float* label = (const float*)d_in[1];
    const float* Ww    = (const float*)d_in[2];
    const float* Wb    = (const float*)d_in[3];
    const float* Uw    = (const float*)d_in[4];
    const float* Ub    = (const float*)d_in[5];
    const float* vw    = (const float*)d_in[6];
    // d_in[7] = vb (cancels in softmax)
    const float* betaw = (const float*)d_in[8];
    const float* betab = (const float*)d_in[9];
    const float* ihw   = (const float*)d_in[10];
    const float* ihb   = (const float*)d_in[11];
    const float* icw   = (const float*)d_in[12];
    const float* icb   = (const float*)d_in[13];
    const float* Wih   = (const float*)d_in[14];
    const float* Whh   = (const float*)d_in[15];
    const float* bih   = (const float*)d_in[16];
    const float* bhh   = (const float*)d_in[17];
    const float* ow    = (const float*)d_in[18];
    const float* ob    = (const float*)d_in[19];

    char* ws = (char*)d_ws;
    unsigned short* h0       = (unsigned short*)(ws + OFF_H0);
    float*          c0       = (float*)(ws + OFF_C0);
    unsigned short* parts_bf = (unsigned short*)(ws + OFF_PARTS);
    unsigned short* Wbig     = (unsigned short*)(ws + OFF_WBIG);
    unsigned short* Wsmall   = (unsigned short*)(ws + OFF_WSMALL);
    unsigned short* Ww2      = (unsigned short*)(ws + OFF_WW2);
    float*          bias     = (float*)(ws + OFF_BIAS);
    float*          avg      = (float*)(ws + OFF_AVG);

    float* out_logits = (float*)d_out;
    float* out_alpha  = out_logits + (size_t)2048 * 256 * 12;

    k_avg<<<512, 256, 0, stream>>>(img, avg);
    k_prep<<<2048, 256, 0, stream>>>(Whh, Wih, Uw, betaw, Ww, bih, bhh, Wbig, Wsmall, Ww2, bias);
    k_h0c0<<<256, 512, 0, stream>>>(avg, ihw, ihb, icw, icb, h0, c0);
    k_parts<<<2048, 256, 0, stream>>>(img, parts_bf);

    k_scan<<<128, 512, 0, stream>>>(h0, c0, parts_bf, Wsmall, Wbig, Ww2, bias,
                                    Ub, betab, Wb, vw, label, ow, ob,
                                    out_alpha, out_logits);
}

// Round 9
// 16312.407 us; speedup vs baseline: 2.1758x; 2.1758x over previous
//
#include <hip/hip_runtime.h>
#include <hip/hip_bf16.h>

// Persistent tile-owner decoder, L3-coherent exchange (no fences, no invalidates).
// 256 blocks x 512 thr, 1 block/CU. ntile=bk&15, mtile=bk>>4. Group = mtile:
// 16 consecutive blocks own batch rows [mtile*128,+128) end-to-end; groups never
// communicate. Shared state (xh h|x|ctx) moves ONLY via sc0 sc1 loads/stores
// (L1+L2 bypass -> Infinity Cache is the coherence point; correct for any XCD
// placement). Weights stay L2-cached forever (no invalidates): Wbig B-tile
// streamed from L2 (per-XCD hot set ~300KB), A-tile staged to LDS per step.
// Barrier: vmcnt(0) -> sc flag store -> 16-lane sc poll. No __threadfence.

typedef __attribute__((ext_vector_type(8))) short short8;
typedef __attribute__((ext_vector_type(4))) float floatx4;

#define DEV static __device__ __forceinline__
#define C2LE 2.885390082f    // 2*log2(e)
#define LOG2E 1.4426950409f
#define LN2 0.6931471806f

DEV unsigned short f2bf(float f) {
    unsigned int u = __float_as_uint(f);
    unsigned int r = (u + 0x7FFFu + ((u >> 16) & 1u)) >> 16;
    return (unsigned short)r;
}
DEV float bf2f(unsigned short u) { return __uint_as_float(((unsigned int)u) << 16); }
DEV float rcp_f(float x) { float r; asm("v_rcp_f32 %0, %1" : "=v"(r) : "v"(x)); return r; }
DEV float tanh_f(float x) { return 1.f - 2.f * rcp_f(1.f + exp2f(x * C2LE)); }
DEV float sigm(float x) { return rcp_f(1.f + exp2f(-x * LOG2E)); }

// ---- L3-coherent (L1+L2 bypass) access helpers ----
DEV void ldg16_sc(short8* d, const unsigned short* p) {
    asm volatile("global_load_dwordx4 %0, %1, off sc0 sc1" : "=v"(*d) : "v"(p));
}
DEV void stg2_sc(unsigned short* p, unsigned short v) {
    unsigned int vv = v;
    asm volatile("global_store_short %0, %1, off sc0 sc1" :: "v"(p), "v"(vv) : "memory");
}
DEV void st_flag(int* p, int v) {
    asm volatile("global_store_dword %0, %1, off sc0 sc1" :: "v"(p), "v"(v) : "memory");
}
DEV int ld_flag(const int* p) {
    int v;
    asm volatile("global_load_dword %0, %1, off sc0 sc1\n\ts_waitcnt vmcnt(0)"
                 : "=v"(v) : "v"(p) : "memory");
    return v;
}

// ---------------- workspace layout (bytes) ----------------
#define OFF_XH0    ((size_t)0)          // bf16 [2048][576]: h(512)|x(12)|ctx(32)|pad0(20)
#define OFF_XH1    ((size_t)2359296)
#define OFF_C0     ((size_t)4718592)    // f32 [2048][512]
#define OFF_PARTS  ((size_t)8912896)    // bf16 [2048][64][32]
#define OFF_WBIG   ((size_t)17301504)   // bf16 [2048][576], perm row p=4j+g <- orig g*512+j
#define OFF_WSMALL ((size_t)19660800)   // bf16 [160][512]: Uw(128), betaw(32)
#define OFF_WW2    ((size_t)19824640)   // bf16 [128][32] = C2LE*Ww
#define OFF_BIAS   ((size_t)19832832)   // f32 [2048] b_ih+b_hh (orig order)
#define OFF_AVG    ((size_t)19841024)   // f32 [2048][64]
#define OFF_FLAGS  ((size_t)20365312)   // int flags[256*32], 128B stride per block

// group barrier via L3: no fences, no invalidates
DEV void gbar(int* flags, int bk, int g16, int step) {
    asm volatile("s_waitcnt vmcnt(0)" ::: "memory");   // this wave's sc-stores reached L3
    __syncthreads();                                    // all waves drained
    if (threadIdx.x < 64) {
        int lane = threadIdx.x;
        if (lane == 0) st_flag(flags + bk * 32, step);
        for (;;) {
            int v = step;
            if (lane < 16) v = ld_flag(flags + (g16 + lane) * 32);
            if (__all(v >= step)) break;
            __builtin_amdgcn_s_sleep(1);
        }
    }
    __syncthreads();
}

__global__ void k_init(int* flags) {
    int i = blockIdx.x * 256 + threadIdx.x;
    if (i < 256 * 32) flags[i] = 0;
}

__global__ void k_avg(const float* __restrict__ img, float* __restrict__ avg) {
    int idx = blockIdx.x * 256 + threadIdx.x;
    int b = idx >> 6, p = idx & 63;
    const float* base = img + (size_t)b * 2048 + p;
    float s = 0.f;
#pragma unroll
    for (int k = 0; k < 32; ++k) s += base[k * 64];
    avg[idx] = s * (1.f / 32.f);
}

__global__ void k_prep(const float* __restrict__ Whh, const float* __restrict__ Wih,
                       const float* __restrict__ Uw, const float* __restrict__ betaw,
                       const float* __restrict__ Ww, const float* __restrict__ bih,
                       const float* __restrict__ bhh,
                       unsigned short* __restrict__ Wbig, unsigned short* __restrict__ Wsmall,
                       unsigned short* __restrict__ Ww2, float* __restrict__ bias_cat) {
    int p = blockIdx.x, tid = threadIdx.x;
    int g = p & 3, j = p >> 2, orig = g * 512 + j;
    for (int k = tid; k < 576; k += 256) {
        float v = 0.f;
        if (k < 512) v = Whh[(size_t)orig * 512 + k];
        else if (k < 556) v = Wih[(size_t)orig * 44 + (k - 512)];
        Wbig[(size_t)p * 576 + k] = f2bf(v);
    }
    if (p < 160) {
        for (int k = tid; k < 512; k += 256) {
            float v = (p < 128) ? Uw[(size_t)p * 512 + k] : betaw[(size_t)(p - 128) * 512 + k];
            Wsmall[(size_t)p * 512 + k] = f2bf(v);
        }
    }
    if (p < 128 && tid < 32) Ww2[p * 32 + tid] = f2bf(C2LE * Ww[p * 32 + tid]);
    if (tid == 0) bias_cat[orig] = bih[orig] + bhh[orig];
}

__global__ __launch_bounds__(512) void k_h0c0(const float* __restrict__ avg,
                                              const float* __restrict__ ihw, const float* __restrict__ ihb,
                                              const float* __restrict__ icw, const float* __restrict__ icb,
                                              unsigned short* __restrict__ xh0, unsigned short* __restrict__ xh1,
                                              float* __restrict__ c0) {
    __shared__ float avg_s[8][64];
    int b0 = blockIdx.x * 8, tid = threadIdx.x;
    for (int i = tid; i < 8 * 64; i += 512) avg_s[i >> 6][i & 63] = avg[b0 * 64 + i];
    __syncthreads();
    int j = tid;
    float w0[64];
#pragma unroll
    for (int p4 = 0; p4 < 16; ++p4) {
        float4 v = ((const float4*)(ihw + j * 64))[p4];
        w0[p4 * 4 + 0] = v.x; w0[p4 * 4 + 1] = v.y; w0[p4 * 4 + 2] = v.z; w0[p4 * 4 + 3] = v.w;
    }
    float bh = ihb[j];
#pragma unroll
    for (int bb = 0; bb < 8; ++bb) {
        float s = bh;
#pragma unroll
        for (int p = 0; p < 64; ++p) s += w0[p] * avg_s[bb][p];
        xh0[(size_t)(b0 + bb) * 576 + j] = f2bf(tanh_f(s));
        if (j < 20) {
            xh0[(size_t)(b0 + bb) * 576 + 556 + j] = 0;
            xh1[(size_t)(b0 + bb) * 576 + 556 + j] = 0;
        }
    }
#pragma unroll
    for (int p4 = 0; p4 < 16; ++p4) {
        float4 v = ((const float4*)(icw + j * 64))[p4];
        w0[p4 * 4 + 0] = v.x; w0[p4 * 4 + 1] = v.y; w0[p4 * 4 + 2] = v.z; w0[p4 * 4 + 3] = v.w;
    }
    float bc = icb[j];
#pragma unroll
    for (int bb = 0; bb < 8; ++bb) {
        float s = bc;
#pragma unroll
        for (int p = 0; p < 64; ++p) s += w0[p] * avg_s[bb][p];
        c0[(size_t)(b0 + bb) * 512 + j] = tanh_f(s);
    }
}

// parts_bf[b][p][k] = bf16(img[b][k][p])
__global__ __launch_bounds__(256) void k_parts(const float* __restrict__ img,
                                               unsigned short* __restrict__ parts_bf) {
    __shared__ float pl[64][33];
    int b = blockIdx.x, tid = threadIdx.x;
    const float* ib = img + (size_t)b * 2048;
    for (int i = tid; i < 2048; i += 256) pl[i & 63][i >> 6] = ib[i];
    __syncthreads();
    for (int i = tid; i < 2048; i += 256)
        parts_bf[(size_t)b * 2048 + i] = f2bf(pl[i >> 5][i & 31]);
}

__global__ __launch_bounds__(512, 2) void k_scan(
    unsigned short* __restrict__ xh0, unsigned short* __restrict__ xh1,
    const float* __restrict__ c0,
    const unsigned short* __restrict__ parts_bf,
    const unsigned short* __restrict__ Wsmall, const unsigned short* __restrict__ Wbig,
    const unsigned short* __restrict__ Ww2, const float* __restrict__ bias_cat,
    const float* __restrict__ Ub, const float* __restrict__ betab, const float* __restrict__ Wb,
    const float* __restrict__ vw,
    const float* __restrict__ label, const float* __restrict__ ow, const float* __restrict__ ob,
    float* __restrict__ out_alpha, float* __restrict__ out_logits,
    int* __restrict__ flags)
{
    __shared__ unsigned short Ald[128 * 584];  // 149.5 KB A-tile (h|x|ctx), pad 584
    __shared__ float uh_l[8][160];             // 5 KB
    __shared__ float al_l[8][64];              // 2 KB
    __shared__ float vw2_l[128];
    __shared__ float bias_sl[128];

    const int tid = threadIdx.x, w = tid >> 6, lane = tid & 63;
    const int bk = blockIdx.x;
    const int mtile = bk >> 4, ntile = bk & 15;   // group = mtile (consecutive bks)
    const int g16 = mtile * 16;
    const int wm = w >> 2, wn = w & 3;

    if (tid < 128) {
        vw2_l[tid] = -2.f * vw[tid];
        bias_sl[tid] = bias_cat[(tid >> 5) * 512 + ntile * 32 + (tid & 31)];
    }
    // c registers: cell (b,j) = (mtile*128+wm*64+mf*16+(lane>>4)*4+r, ntile*32+wn*8+nf*4+(lane&3))
    float creg[32];
#pragma unroll
    for (int mf = 0; mf < 4; ++mf)
#pragma unroll
        for (int nf = 0; nf < 2; ++nf)
#pragma unroll
            for (int r = 0; r < 4; ++r) {
                int b = mtile * 128 + wm * 64 + mf * 16 + (lane >> 4) * 4 + r;
                int j = ntile * 32 + wn * 8 + nf * 4 + (lane & 3);
                creg[(mf * 2 + nf) * 4 + r] = c0[(size_t)b * 512 + j];
            }
    __syncthreads();
    float vwsum = 0.f;
#pragma unroll
    for (int d = 0; d < 128; ++d) vwsum += vw2_l[d];
    vwsum *= -0.5f;

    // ---- stage full A-tile (128 rows x 576) from global xin -> LDS via sc loads ----
    auto stage_A = [&](const unsigned short* xin) {
#pragma unroll
        for (int half = 0; half < 2; ++half) {
            short8 tmp[9];
#pragma unroll
            for (int q = 0; q < 9; ++q) {
                int cid = tid + (half * 9 + q) * 512;       // 9216 chunks of 16B
                int row = cid / 72, c16 = cid % 72;
                ldg16_sc(&tmp[q], xin + (size_t)(mtile * 128 + row) * 576 + c16 * 8);
            }
            asm volatile("s_waitcnt vmcnt(0)" ::: "memory");
            __builtin_amdgcn_sched_barrier(0);
#pragma unroll
            for (int q = 0; q < 9; ++q) {
                int cid = tid + (half * 9 + q) * 512;
                int row = cid / 72, c16 = cid % 72;
                *(short8*)&Ald[row * 584 + c16 * 8] = tmp[q];
            }
        }
    };

    // ---- phase 1: gates GEMM (A from LDS, B from L2) + fused cell -> h2 sc-stores ----
    auto phase1 = [&](unsigned short* xout) {
        const unsigned short* Bp = Wbig + (size_t)(ntile * 128 + wn * 32 + (lane & 15)) * 576 + (lane >> 4) * 8;
        const unsigned short* Ab = &Ald[(wm * 64 + (lane & 15)) * 584 + (lane >> 4) * 8];
        floatx4 acc[4][2] = {};
#pragma unroll 3
        for (int kk = 0; kk < 18; ++kk) {
            int k0 = kk * 32;
            short8 b0 = *(const short8*)(Bp + k0);
            short8 b1 = *(const short8*)(Bp + 16 * 576 + k0);
#pragma unroll
            for (int mf = 0; mf < 4; ++mf) {
                short8 a = *(const short8*)(Ab + mf * 16 * 584 + k0);
                acc[mf][0] = __builtin_amdgcn_mfma_f32_16x16x32_bf16(a, b0, acc[mf][0], 0, 0, 0);
                acc[mf][1] = __builtin_amdgcn_mfma_f32_16x16x32_bf16(a, b1, acc[mf][1], 0, 0, 0);
            }
        }
        int base = (lane & 48) | (4 * (lane & 3));
        int jl = wn * 8 + (lane & 3);
#pragma unroll
        for (int mf = 0; mf < 4; ++mf)
#pragma unroll
            for (int nf = 0; nf < 2; ++nf) {
#pragma unroll
                for (int r = 0; r < 4; ++r) {
                    float x = acc[mf][nf][r];
                    float g0 = __shfl(x, base + 0);
                    float g1 = __shfl(x, base + 1);
                    float g2 = __shfl(x, base + 2);
                    float g3 = __shfl(x, base + 3);
                    int jj = jl + nf * 4;
                    float gi = g0 + bias_sl[jj];
                    float gf = g1 + bias_sl[32 + jj];
                    float gg = g2 + bias_sl[64 + jj];
                    float go = g3 + bias_sl[96 + jj];
                    int ci = (mf * 2 + nf) * 4 + r;
                    float c2 = sigm(gf) * creg[ci] + sigm(gi) * tanh_f(gg);
                    creg[ci] = c2;
                    float h2 = sigm(go) * tanh_f(c2);
                    if (((lane >> 2) & 3) == 0) {
                        int bg = mtile * 128 + wm * 64 + mf * 16 + (lane >> 4) * 4 + r;
                        stg2_sc(xout + (size_t)bg * 576 + ntile * 32 + jj, f2bf(h2));
                    }
                }
            }
    };

    // ---- phase 2: stage 8 owner rows -> head(tt-1) + Uh + attention(tt) ----
    auto phase2 = [&](int tt, unsigned short* xb, bool do_head, bool do_attn) {
        {   // stage owner rows (h cols 0:512) into Ald rows ntile*8..+8
            int row = tid >> 6, c16 = tid & 63;
            short8 tv;
            ldg16_sc(&tv, xb + (size_t)(bk * 8 + row) * 576 + c16 * 8);
            asm volatile("s_waitcnt vmcnt(0)" ::: "memory");
            __builtin_amdgcn_sched_barrier(0);
            *(short8*)&Ald[(ntile * 8 + row) * 584 + c16 * 8] = tv;
        }
        __syncthreads();
        int b = bk * 8 + w;
        if (do_head) {
            short8 hv = *(const short8*)&Ald[(ntile * 8 + w) * 584 + lane * 8];
            float hf[8];
#pragma unroll
            for (int j = 0; j < 8; ++j) hf[j] = bf2f((unsigned short)hv[j]);
            float ov[12];
#pragma unroll
            for (int v = 0; v < 12; ++v) {
                const float* owr = ow + v * 512 + lane * 8;
                float4 o0 = *(const float4*)owr;
                float4 o1 = *(const float4*)(owr + 4);
                float p = hf[0] * o0.x + hf[1] * o0.y + hf[2] * o0.z + hf[3] * o0.w
                        + hf[4] * o1.x + hf[5] * o1.y + hf[6] * o1.z + hf[7] * o1.w;
#pragma unroll
                for (int o = 32; o; o >>= 1) p += __shfl_xor(p, o);
                ov[v] = p + ob[v];
            }
            float mx = ov[0];
#pragma unroll
            for (int v = 1; v < 12; ++v) mx = fmaxf(mx, ov[v]);
            float ss = 0.f;
#pragma unroll
            for (int v = 0; v < 12; ++v) ss += exp2f((ov[v] - mx) * LOG2E);
            float lse = mx + log2f(ss) * LN2;
#pragma unroll
            for (int v = 0; v < 12; ++v)
                if (lane == v) out_logits[((size_t)b * 256 + (tt - 1)) * 12 + v] = ov[v] - lse;
        }
        if (do_attn && w < 5) {
            // Uh[8][160] = h[8x512] @ Wsmall^T; A from LDS (rows dup via lane&7)
            const unsigned short* Bp = Wsmall + (size_t)(w * 32 + (lane & 15)) * 512 + (lane >> 4) * 8;
            const unsigned short* Ab = &Ald[(ntile * 8 + (lane & 7)) * 584 + (lane >> 4) * 8];
            floatx4 u0 = {}, u1 = {};
#pragma unroll 4
            for (int k0 = 0; k0 < 512; k0 += 32) {
                short8 a = *(const short8*)(Ab + k0);
                u0 = __builtin_amdgcn_mfma_f32_16x16x32_bf16(a, *(const short8*)(Bp + k0), u0, 0, 0, 0);
                u1 = __builtin_amdgcn_mfma_f32_16x16x32_bf16(a, *(const short8*)(Bp + 16 * 512 + k0), u1, 0, 0, 0);
            }
            int r0 = (lane >> 4) * 4, cc = lane & 15;
            if (r0 < 8) {
#pragma unroll
                for (int q = 0; q < 2; ++q) {
                    int n = w * 32 + q * 16 + cc;
#pragma unroll
                    for (int r = 0; r < 4; ++r) {
                        float val = (q ? u1[r] : u0[r]);
                        uh_l[r0 + r][n] = (n < 128) ? C2LE * (val + Ub[n] + Wb[n])
                                                    : (val + betab[n - 128]);
                    }
                }
            }
        }
        __syncthreads();
        if (do_attn) {
            const unsigned short* pb = parts_bf + (size_t)b * 2048;
            short8 pa[4];
#pragma unroll
            for (int mt = 0; mt < 4; ++mt)
                pa[mt] = *(const short8*)(pb + ((lane & 15) + 16 * mt) * 32 + (lane >> 4) * 8);
            float sc[4][4] = {};
#pragma unroll
            for (int nt = 0; nt < 8; ++nt) {
                short8 wwf = *(const short8*)(Ww2 + (size_t)((lane & 15) + 16 * nt) * 32 + (lane >> 4) * 8);
                int d = nt * 16 + (lane & 15);
                float ud = uh_l[w][d];
                float v2 = vw2_l[d];
#pragma unroll
                for (int mt = 0; mt < 4; ++mt) {
                    floatx4 z = {};
                    floatx4 wsa = __builtin_amdgcn_mfma_f32_16x16x32_bf16(pa[mt], wwf, z, 0, 0, 0);
#pragma unroll
                    for (int r = 0; r < 4; ++r)
                        sc[mt][r] += v2 * rcp_f(1.f + exp2f(wsa[r] + ud));
                }
            }
            float mx = -1e30f;
#pragma unroll
            for (int mt = 0; mt < 4; ++mt)
#pragma unroll
                for (int r = 0; r < 4; ++r) {
                    float s = sc[mt][r];
                    s += __shfl_xor(s, 1); s += __shfl_xor(s, 2);
                    s += __shfl_xor(s, 4); s += __shfl_xor(s, 8);
                    s += vwsum;
                    sc[mt][r] = s;
                    mx = fmaxf(mx, s);
                }
            mx = fmaxf(mx, __shfl_xor(mx, 16));
            mx = fmaxf(mx, __shfl_xor(mx, 32));
            float ssum = 0.f;
            float av[4][4];
#pragma unroll
            for (int mt = 0; mt < 4; ++mt)
#pragma unroll
                for (int r = 0; r < 4; ++r) {
                    av[mt][r] = exp2f((sc[mt][r] - mx) * LOG2E);
                    ssum += av[mt][r];
                }
            ssum += __shfl_xor(ssum, 16);
            ssum += __shfl_xor(ssum, 32);
            float rs = rcp_f(ssum);
#pragma unroll
            for (int mt = 0; mt < 4; ++mt) {
                if ((lane & 15) == mt) {
                    float4 fv = make_float4(av[mt][0] * rs, av[mt][1] * rs, av[mt][2] * rs, av[mt][3] * rs);
                    int p0 = mt * 16 + (lane >> 4) * 4;
                    *(float4*)&out_alpha[((size_t)tt * 2048 + b) * 64 + p0] = fv;
                    *(float4*)&al_l[w][p0] = fv;
                }
            }
            int k = lane & 31, half = lane >> 5;
            float cp = 0.f;
#pragma unroll
            for (int p = 0; p < 32; ++p) {
                int pp = half * 32 + p;
                cp += al_l[w][pp] * bf2f(parts_bf[(size_t)b * 2048 + pp * 32 + k]);
            }
            cp += __shfl_xor(cp, 32);
            if (half == 0) {
                float beta = sigm(uh_l[w][128 + k]);
                stg2_sc(xb + (size_t)b * 576 + 524 + k, f2bf(cp * beta));
            }
            if (lane < 12)
                stg2_sc(xb + (size_t)b * 576 + 512 + lane, f2bf(label[((size_t)b * 256 + tt) * 12 + lane]));
        }
    };

    int bc = 0;
    phase2(0, xh0, false, true);
    gbar(flags, bk, g16, ++bc);
    for (int t = 0; t < 256; ++t) {
        const unsigned short* xin = (t & 1) ? xh1 : xh0;
        unsigned short* xout = (t & 1) ? xh0 : xh1;
        stage_A(xin);
        __syncthreads();
        phase1(xout);
        gbar(flags, bk, g16, ++bc);
        phase2(t + 1, xout, true, t < 255);
        if (t < 255) gbar(flags, bk, g16, ++bc);
    }
}

extern "C" void kernel_launch(void* const* d_in, const int* in_sizes, int n_in,
                              void* d_out, int out_size, void* d_ws, size_t ws_size,
                              hipStream_t stream) {
    const float* img   = (const float*)d_in[0];
    const float* label = (const float*)d_in[1];
    const float* Ww    = (const float*)d_in[2];
    const float* Wb    = (const float*)d_in[3];
    const float* Uw    = (const float*)d_in[4];
    const float* Ub    = (const float*)d_in[5];
    const float* vw    = (const float*)d_in[6];
    // d_in[7] = vb (cancels in softmax)
    const float* betaw = (const float*)d_in[8];
    const float* betab = (const float*)d_in[9];
    const float* ihw   = (const float*)d_in[10];
    const float* ihb   = (const float*)d_in[11];
    const float* icw   = (const float*)d_in[12];
    const float* icb   = (const float*)d_in[13];
    const float* Wih   = (const float*)d_in[14];
    const float* Whh   = (const float*)d_in[15];
    const float* bih   = (const float*)d_in[16];
    const float* bhh   = (const float*)d_in[17];
    const float* ow    = (const float*)d_in[18];
    const float* ob    = (const float*)d_in[19];

    char* ws = (char*)d_ws;
    unsigned short* xh0      = (unsigned short*)(ws + OFF_XH0);
    unsigned short* xh1      = (unsigned short*)(ws + OFF_XH1);
    float*          c0       = (float*)(ws + OFF_C0);
    unsigned short* parts_bf = (unsigned short*)(ws + OFF_PARTS);
    unsigned short* Wbig     = (unsigned short*)(ws + OFF_WBIG);
    unsigned short* Wsmall   = (unsigned short*)(ws + OFF_WSMALL);
    unsigned short* Ww2      = (unsigned short*)(ws + OFF_WW2);
    float*          bias     = (float*)(ws + OFF_BIAS);
    float*          avg      = (float*)(ws + OFF_AVG);
    int*            flags    = (int*)(ws + OFF_FLAGS);

    float* out_logits = (float*)d_out;
    float* out_alpha  = out_logits + (size_t)2048 * 256 * 12;

    k_init<<<32, 256, 0, stream>>>(flags);
    k_avg<<<512, 256, 0, stream>>>(img, avg);
    k_prep<<<2048, 256, 0, stream>>>(Whh, Wih, Uw, betaw, Ww, bih, bhh, Wbig, Wsmall, Ww2, bias);
    k_h0c0<<<256, 512, 0, stream>>>(avg, ihw, ihb, icw, icb, xh0, xh1, c0);
    k_parts<<<2048, 256, 0, stream>>>(img, parts_bf);

    k_scan<<<256, 512, 0, stream>>>(xh0, xh1, c0, parts_bf, Wsmall, Wbig, Ww2, bias,
                                    Ub, betab, Wb, vw, label, ow, ob,
                                    out_alpha, out_logits, flags);
}

// Round 10
// 15221.599 us; speedup vs baseline: 2.3317x; 1.0717x over previous
//
#include <hip/hip_runtime.h>
#include <hip/hip_bf16.h>

// Persistent tile-owner decoder v2: G=64 groups x P=4 blocks. 256 blocks x 512thr,
// 1 block/CU. Block bk: mtile=bk>>2 (32 rows [mtile*32,+32)), ntile=bk&3
// (512 perm-cols [ntile*512,+512)). Groups never communicate; barrier = 4 flags.
// All xh exchange via sc0 sc1 (L3-coherent, R9-proven: no fences, no invalidates,
// L2 stays weight-hot). sc-read/step = 9.4MB (was 37.7 R9); B streams from L2
// (590KB/block/step, 18.9MB/XCD < resident 2.36MB Wbig... full Wbig L2-resident).
// Step: phase1 (gates GEMM A-LDS x B-L2 + fused cell, packed dwordx2 h2 stores)
//  -> gbarA -> stage owner 8 rows -> head(t) + Uh -> sync ->
//  [issue 24-row stage under attention(t+1), x/ctx packed stores] -> gbarB ->
//  stage tail (x/ctx cols) -> next.

typedef __attribute__((ext_vector_type(8))) short short8;
typedef __attribute__((ext_vector_type(4))) float floatx4;
typedef __attribute__((ext_vector_type(2))) unsigned int uint2v;

#define DEV static __device__ __forceinline__
#define C2LE 2.885390082f    // 2*log2(e)
#define LOG2E 1.4426950409f
#define LN2 0.6931471806f

DEV unsigned short f2bf(float f) {
    unsigned int u = __float_as_uint(f);
    unsigned int r = (u + 0x7FFFu + ((u >> 16) & 1u)) >> 16;
    return (unsigned short)r;
}
DEV float bf2f(unsigned short u) { return __uint_as_float(((unsigned int)u) << 16); }
DEV float rcp_f(float x) { float r; asm("v_rcp_f32 %0, %1" : "=v"(r) : "v"(x)); return r; }
DEV float tanh_f(float x) { return 1.f - 2.f * rcp_f(1.f + exp2f(x * C2LE)); }
DEV float sigm(float x) { return rcp_f(1.f + exp2f(-x * LOG2E)); }

// ---- L3-coherent (L1+L2 bypass) helpers [R9-proven] ----
DEV void ldg16_sc(short8* d, const unsigned short* p) {
    asm volatile("global_load_dwordx4 %0, %1, off sc0 sc1" : "=v"(*d) : "v"(p));
}
DEV void stg8_sc(unsigned short* p, uint2v v) {
    asm volatile("global_store_dwordx2 %0, %1, off sc0 sc1" :: "v"(p), "v"(v) : "memory");
}
DEV void st_flag(int* p, int v) {
    asm volatile("global_store_dword %0, %1, off sc0 sc1" :: "v"(p), "v"(v) : "memory");
}
DEV int ld_flag(const int* p) {
    int v;
    asm volatile("global_load_dword %0, %1, off sc0 sc1\n\ts_waitcnt vmcnt(0)"
                 : "=v"(v) : "v"(p) : "memory");
    return v;
}
DEV void waitv0() { asm volatile("s_waitcnt vmcnt(0)" ::: "memory"); }

// ---------------- workspace layout (bytes) ----------------
#define OFF_XH     ((size_t)0)          // bf16 [2048][576]: h|x|ctx|pad0(20)
#define OFF_C0     ((size_t)2359296)    // f32 [2048][512]
#define OFF_PARTS  ((size_t)6553600)    // bf16 [2048][64][32]
#define OFF_WBIG   ((size_t)14942208)   // bf16 [2048][576], perm p=4j+g <- orig g*512+j
#define OFF_WSMALL ((size_t)17301504)   // bf16 [160][512]
#define OFF_WW2    ((size_t)17465344)   // bf16 [128][32] = C2LE*Ww
#define OFF_BIAS   ((size_t)17473536)   // f32 [2048]
#define OFF_AVG    ((size_t)17481728)   // f32 [2048][64]
#define OFF_FLAGS  ((size_t)18006016)   // int [256*32]

// group barrier (P=4), per-block flag, no fences
DEV void gbar(int* flags, int bk, int g4, int step) {
    waitv0();
    __syncthreads();
    if (threadIdx.x < 64) {
        int lane = threadIdx.x;
        if (lane == 0) st_flag(flags + bk * 32, step);
        for (;;) {
            int v = step;
            if (lane < 4) v = ld_flag(flags + (g4 + lane) * 32);
            if (__all(v >= step)) break;
            __builtin_amdgcn_s_sleep(1);
        }
    }
    __syncthreads();
}

__global__ void k_init(int* flags) {
    int i = blockIdx.x * 256 + threadIdx.x;
    if (i < 256 * 32) flags[i] = 0;
}

__global__ void k_avg(const float* __restrict__ img, float* __restrict__ avg) {
    int idx = blockIdx.x * 256 + threadIdx.x;
    int b = idx >> 6, p = idx & 63;
    const float* base = img + (size_t)b * 2048 + p;
    float s = 0.f;
#pragma unroll
    for (int k = 0; k < 32; ++k) s += base[k * 64];
    avg[idx] = s * (1.f / 32.f);
}

__global__ void k_prep(const float* __restrict__ Whh, const float* __restrict__ Wih,
                       const float* __restrict__ Uw, const float* __restrict__ betaw,
                       const float* __restrict__ Ww, const float* __restrict__ bih,
                       const float* __restrict__ bhh,
                       unsigned short* __restrict__ Wbig, unsigned short* __restrict__ Wsmall,
                       unsigned short* __restrict__ Ww2, float* __restrict__ bias_cat) {
    int p = blockIdx.x, tid = threadIdx.x;
    int g = p & 3, j = p >> 2, orig = g * 512 + j;
    for (int k = tid; k < 576; k += 256) {
        float v = 0.f;
        if (k < 512) v = Whh[(size_t)orig * 512 + k];
        else if (k < 556) v = Wih[(size_t)orig * 44 + (k - 512)];
        Wbig[(size_t)p * 576 + k] = f2bf(v);
    }
    if (p < 160) {
        for (int k = tid; k < 512; k += 256) {
            float v = (p < 128) ? Uw[(size_t)p * 512 + k] : betaw[(size_t)(p - 128) * 512 + k];
            Wsmall[(size_t)p * 512 + k] = f2bf(v);
        }
    }
    if (p < 128 && tid < 32) Ww2[p * 32 + tid] = f2bf(C2LE * Ww[p * 32 + tid]);
    if (tid == 0) bias_cat[orig] = bih[orig] + bhh[orig];
}

__global__ __launch_bounds__(512) void k_h0c0(const float* __restrict__ avg,
                                              const float* __restrict__ ihw, const float* __restrict__ ihb,
                                              const float* __restrict__ icw, const float* __restrict__ icb,
                                              unsigned short* __restrict__ xh, float* __restrict__ c0) {
    __shared__ float avg_s[8][64];
    int b0 = blockIdx.x * 8, tid = threadIdx.x;
    for (int i = tid; i < 8 * 64; i += 512) avg_s[i >> 6][i & 63] = avg[b0 * 64 + i];
    __syncthreads();
    int j = tid;
    float w0[64];
#pragma unroll
    for (int p4 = 0; p4 < 16; ++p4) {
        float4 v = ((const float4*)(ihw + j * 64))[p4];
        w0[p4 * 4 + 0] = v.x; w0[p4 * 4 + 1] = v.y; w0[p4 * 4 + 2] = v.z; w0[p4 * 4 + 3] = v.w;
    }
    float bh = ihb[j];
#pragma unroll
    for (int bb = 0; bb < 8; ++bb) {
        float s = bh;
#pragma unroll
        for (int p = 0; p < 64; ++p) s += w0[p] * avg_s[bb][p];
        xh[(size_t)(b0 + bb) * 576 + j] = f2bf(tanh_f(s));
        if (j < 20) xh[(size_t)(b0 + bb) * 576 + 556 + j] = 0;   // zero pad cols
    }
#pragma unroll
    for (int p4 = 0; p4 < 16; ++p4) {
        float4 v = ((const float4*)(icw + j * 64))[p4];
        w0[p4 * 4 + 0] = v.x; w0[p4 * 4 + 1] = v.y; w0[p4 * 4 + 2] = v.z; w0[p4 * 4 + 3] = v.w;
    }
    float bc = icb[j];
#pragma unroll
    for (int bb = 0; bb < 8; ++bb) {
        float s = bc;
#pragma unroll
        for (int p = 0; p < 64; ++p) s += w0[p] * avg_s[bb][p];
        c0[(size_t)(b0 + bb) * 512 + j] = tanh_f(s);
    }
}

// parts_bf[b][p][k] = bf16(img[b][k][p])
__global__ __launch_bounds__(256) void k_parts(const float* __restrict__ img,
                                               unsigned short* __restrict__ parts_bf) {
    __shared__ float pl[64][33];
    int b = blockIdx.x, tid = threadIdx.x;
    const float* ib = img + (size_t)b * 2048;
    for (int i = tid; i < 2048; i += 256) pl[i & 63][i >> 6] = ib[i];
    __syncthreads();
    for (int i = tid; i < 2048; i += 256)
        parts_bf[(size_t)b * 2048 + i] = f2bf(pl[i >> 5][i & 31]);
}

__global__ __launch_bounds__(512, 2) void k_scan(
    unsigned short* __restrict__ xh,
    const float* __restrict__ c0,
    const unsigned short* __restrict__ parts_bf,
    const unsigned short* __restrict__ Wsmall, const unsigned short* __restrict__ Wbig,
    const unsigned short* __restrict__ Ww2, const float* __restrict__ bias_cat,
    const float* __restrict__ Ub, const float* __restrict__ betab, const float* __restrict__ Wb,
    const float* __restrict__ vw,
    const float* __restrict__ label, const float* __restrict__ ow, const float* __restrict__ ob,
    float* __restrict__ out_alpha, float* __restrict__ out_logits,
    int* __restrict__ flags)
{
    __shared__ unsigned short Ald[32 * 584];      // 36.5 KB A-tile (32 rows x 576, pad)
    __shared__ unsigned short parts_l[8][2304];   // 36.9 KB [row][p*36+k]
    __shared__ unsigned short ow_l[12][512];      // 12.3 KB
    __shared__ float uh_l[8][160];                // 5 KB
    __shared__ float al_l[8][64];                 // 2 KB
    __shared__ float bias_l[512];                 // 2 KB [g*128 + jl]
    __shared__ unsigned short xscr[8][48];        // x/ctx pack scratch
    __shared__ float vw2_l[128];
    __shared__ float obl[12];

    const int tid = threadIdx.x, w = tid >> 6, lane = tid & 63;
    const int bk = blockIdx.x;
    const int mtile = bk >> 2, ntile = bk & 3;
    const int g4 = bk & ~3;
    const int wm = w >> 2, wn = w & 3;          // wave tile: rows[wm*16,+16) x cols[wn*128,+128)

    // ---- one-time LDS staging ----
    if (tid < 128) vw2_l[tid] = -2.f * vw[tid];
    if (tid < 12) obl[tid] = ob[tid];
    if (tid < 512) {
        int g = tid >> 7, jl = tid & 127;
        bias_l[tid] = bias_cat[g * 512 + ntile * 128 + jl];
    }
    for (int i = tid; i < 12 * 512; i += 512) ow_l[i >> 9][i & 511] = f2bf(ow[i]);
    {
        int row = tid >> 6, p = tid & 63;   // 512 = 8*64
        const short8* src = (const short8*)(parts_bf + (size_t)(bk * 8 + row) * 2048 + p * 32);
        short8* dst = (short8*)&parts_l[row][p * 36];
        dst[0] = src[0]; dst[1] = src[1]; dst[2] = src[2]; dst[3] = src[3];
    }
    // c registers: cell (b, j) = (mtile*32 + wm*16 + (lane>>4)*4 + r,
    //                             ntile*128 + wn*32 + nf*4 + (lane&3)); creg[nf*4+r]
    float creg[32];
#pragma unroll
    for (int nf = 0; nf < 8; ++nf)
#pragma unroll
        for (int r = 0; r < 4; ++r) {
            int b = mtile * 32 + wm * 16 + (lane >> 4) * 4 + r;
            int j = ntile * 128 + wn * 32 + nf * 4 + (lane & 3);
            creg[nf * 4 + r] = c0[(size_t)b * 512 + j];
        }
    // prologue stage: all 32 rows, h cols (0:512)
    {
        short8 tv[4];
#pragma unroll
        for (int q = 0; q < 4; ++q) {
            int cid = tid + q * 512;          // 2048 chunks
            int row = cid >> 6, c16 = cid & 63;
            ldg16_sc(&tv[q], xh + (size_t)(mtile * 32 + row) * 576 + c16 * 8);
        }
        waitv0();
        __builtin_amdgcn_sched_barrier(0);
#pragma unroll
        for (int q = 0; q < 4; ++q) {
            int cid = tid + q * 512;
            int row = cid >> 6, c16 = cid & 63;
            *(short8*)&Ald[row * 584 + c16 * 8] = tv[q];
        }
    }
    __syncthreads();
    float vwsum = 0.f;
#pragma unroll
    for (int d = 0; d < 128; ++d) vwsum += vw2_l[d];
    vwsum *= -0.5f;

    // ---- Uh GEMM: uh_l[8][160] = owner h @ Wsmall^T (waves 0..4) ----
    auto do_uh = [&]() {
        if (w < 5) {
            const unsigned short* Bp = Wsmall + (size_t)(w * 32 + (lane & 15)) * 512 + (lane >> 4) * 8;
            const unsigned short* Ab = &Ald[(ntile * 8 + (lane & 7)) * 584 + (lane >> 4) * 8];
            floatx4 u0 = {}, u1 = {};
#pragma unroll 4
            for (int k0 = 0; k0 < 512; k0 += 32) {
                short8 a = *(const short8*)(Ab + k0);
                u0 = __builtin_amdgcn_mfma_f32_16x16x32_bf16(a, *(const short8*)(Bp + k0), u0, 0, 0, 0);
                u1 = __builtin_amdgcn_mfma_f32_16x16x32_bf16(a, *(const short8*)(Bp + 16 * 512 + k0), u1, 0, 0, 0);
            }
            int r0 = (lane >> 4) * 4, cc = lane & 15;
            if (r0 < 8) {
#pragma unroll
                for (int q = 0; q < 2; ++q) {
                    int n = w * 32 + q * 16 + cc;
#pragma unroll
                    for (int r = 0; r < 4; ++r) {
                        float val = (q ? u1[r] : u0[r]);
                        uh_l[r0 + r][n] = (n < 128) ? C2LE * (val + Ub[n] + Wb[n])
                                                    : (val + betab[n - 128]);
                    }
                }
            }
        }
    };

    // ---- output head: logits[tt] from owner rows (Ald) ----
    auto do_head = [&](int tt) {
        int b = bk * 8 + w;
        short8 hv = *(const short8*)&Ald[(ntile * 8 + w) * 584 + lane * 8];
        float hf[8];
#pragma unroll
        for (int j = 0; j < 8; ++j) hf[j] = bf2f((unsigned short)hv[j]);
        float ov[12];
#pragma unroll
        for (int v = 0; v < 12; ++v) {
            short8 wv = *(const short8*)&ow_l[v][lane * 8];
            float p = 0.f;
#pragma unroll
            for (int j = 0; j < 8; ++j) p += hf[j] * bf2f((unsigned short)wv[j]);
#pragma unroll
            for (int o = 32; o; o >>= 1) p += __shfl_xor(p, o);
            ov[v] = p + obl[v];
        }
        float mx = ov[0];
#pragma unroll
        for (int v = 1; v < 12; ++v) mx = fmaxf(mx, ov[v]);
        float ss = 0.f;
#pragma unroll
        for (int v = 0; v < 12; ++v) ss += exp2f((ov[v] - mx) * LOG2E);
        float lse = mx + log2f(ss) * LN2;
#pragma unroll
        for (int v = 0; v < 12; ++v)
            if (lane == v) out_logits[((size_t)b * 256 + tt) * 12 + v] = ov[v] - lse;
    };

    // ---- attention(tt): score/softmax/ctx; packed x/ctx sc-stores ----
    auto do_attn = [&](int tt) {
        int b = bk * 8 + w;
        short8 pa[4];
#pragma unroll
        for (int mt = 0; mt < 4; ++mt)
            pa[mt] = *(const short8*)&parts_l[w][(mt * 16 + (lane & 15)) * 36 + (lane >> 4) * 8];
        float sc[4][4] = {};
#pragma unroll
        for (int nt = 0; nt < 8; ++nt) {
            short8 wwf = *(const short8*)(Ww2 + (size_t)((lane & 15) + 16 * nt) * 32 + (lane >> 4) * 8);
            int d = nt * 16 + (lane & 15);
            float ud = uh_l[w][d];
            float v2 = vw2_l[d];
#pragma unroll
            for (int mt = 0; mt < 4; ++mt) {
                floatx4 z = {};
                floatx4 wsa = __builtin_amdgcn_mfma_f32_16x16x32_bf16(pa[mt], wwf, z, 0, 0, 0);
#pragma unroll
                for (int r = 0; r < 4; ++r)
                    sc[mt][r] += v2 * rcp_f(1.f + exp2f(wsa[r] + ud));
            }
        }
        float mx = -1e30f;
#pragma unroll
        for (int mt = 0; mt < 4; ++mt)
#pragma unroll
            for (int r = 0; r < 4; ++r) {
                float s = sc[mt][r];
                s += __shfl_xor(s, 1); s += __shfl_xor(s, 2);
                s += __shfl_xor(s, 4); s += __shfl_xor(s, 8);
                s += vwsum;
                sc[mt][r] = s;
                mx = fmaxf(mx, s);
            }
        mx = fmaxf(mx, __shfl_xor(mx, 16));
        mx = fmaxf(mx, __shfl_xor(mx, 32));
        float ssum = 0.f;
        float av[4][4];
#pragma unroll
        for (int mt = 0; mt < 4; ++mt)
#pragma unroll
            for (int r = 0; r < 4; ++r) {
                av[mt][r] = exp2f((sc[mt][r] - mx) * LOG2E);
                ssum += av[mt][r];
            }
        ssum += __shfl_xor(ssum, 16);
        ssum += __shfl_xor(ssum, 32);
        float rs = rcp_f(ssum);
#pragma unroll
        for (int mt = 0; mt < 4; ++mt) {
            if ((lane & 15) == mt) {
                float4 fv = make_float4(av[mt][0] * rs, av[mt][1] * rs, av[mt][2] * rs, av[mt][3] * rs);
                int p0 = mt * 16 + (lane >> 4) * 4;
                *(float4*)&out_alpha[((size_t)tt * 2048 + b) * 64 + p0] = fv;
                *(float4*)&al_l[w][p0] = fv;
            }
        }
        int k = lane & 31, half = lane >> 5;
        float cp = 0.f;
#pragma unroll
        for (int p = 0; p < 32; ++p) {
            int pp = half * 32 + p;
            cp += al_l[w][pp] * bf2f(parts_l[w][pp * 36 + k]);
        }
        cp += __shfl_xor(cp, 32);
        if (half == 0) xscr[w][12 + k] = f2bf(cp * sigm(uh_l[w][128 + k]));
        if (lane < 12) xscr[w][lane] = f2bf(label[((size_t)b * 256 + tt) * 12 + lane]);
        // pack 44 ushorts -> 11 dwordx2 sc stores
        if (lane < 11) {
            uint2v v = *(const uint2v*)&xscr[w][lane * 4];
            stg8_sc(xh + (size_t)b * 576 + 512 + lane * 4, v);
        }
    };

    // ---- phase1: gates GEMM (A LDS x B L2) + fused cell, packed h2 stores ----
    auto phase1 = [&]() {
        const unsigned short* Bp = Wbig + (size_t)(ntile * 512 + wn * 128 + (lane & 15)) * 576 + (lane >> 4) * 8;
        const unsigned short* Ab = &Ald[(wm * 16 + (lane & 15)) * 584 + (lane >> 4) * 8];
        floatx4 acc[8] = {};
#pragma unroll 2
        for (int kk = 0; kk < 18; ++kk) {
            int k0 = kk * 32;
            short8 a = *(const short8*)(Ab + k0);
#pragma unroll
            for (int nf = 0; nf < 8; ++nf) {
                short8 bv = *(const short8*)(Bp + (size_t)nf * 9216 + k0);
                acc[nf] = __builtin_amdgcn_mfma_f32_16x16x32_bf16(a, bv, acc[nf], 0, 0, 0);
            }
        }
        int base = (lane & 48) | ((lane & 3) * 4);
#pragma unroll
        for (int nf = 0; nf < 8; ++nf) {
            int jl = wn * 32 + nf * 4 + (lane & 3);
            float bi = bias_l[jl], bfv = bias_l[128 + jl], bg = bias_l[256 + jl], bo = bias_l[384 + jl];
#pragma unroll
            for (int r = 0; r < 4; ++r) {
                float x = acc[nf][r];
                float g0 = __shfl(x, base + 0);
                float g1 = __shfl(x, base + 1);
                float g2 = __shfl(x, base + 2);
                float g3 = __shfl(x, base + 3);
                int ci = nf * 4 + r;
                float c2 = sigm(g1 + bfv) * creg[ci] + sigm(g0 + bi) * tanh_f(g2 + bg);
                creg[ci] = c2;
                float h2 = sigm(g3 + bo) * tanh_f(c2);
                unsigned int hv = f2bf(h2);
                unsigned int o1 = (unsigned int)__shfl_xor((int)hv, 1) & 0xFFFFu;
                unsigned int pair = (lane & 1) ? (o1 | (hv << 16)) : (hv | (o1 << 16));
                unsigned int o2 = (unsigned int)__shfl_xor((int)pair, 2);
                if ((lane & 15) == 0) {
                    int row = mtile * 32 + wm * 16 + (lane >> 4) * 4 + r;
                    uint2v v; v[0] = pair; v[1] = o2;
                    stg8_sc(xh + (size_t)row * 576 + ntile * 128 + wn * 32 + nf * 4, v);
                }
            }
        }
    };

    // ---- prologue: Uh(0) + attention(0) on h0 ----
    do_uh();
    __syncthreads();
    do_attn(0);
    int bc = 0;
    gbar(flags, bk, g4, ++bc);
    if (tid < 256) {   // stage tail (x0/ctx0 + zeros), cols 512:576
        short8 tv;
        int row = tid >> 3, c16 = tid & 7;
        ldg16_sc(&tv, xh + (size_t)(mtile * 32 + row) * 576 + 512 + c16 * 8);
        waitv0();
        __builtin_amdgcn_sched_barrier(0);
        *(short8*)&Ald[row * 584 + 512 + c16 * 8] = tv;
    }
    __syncthreads();

    for (int t = 0; t < 256; ++t) {
        phase1();
        gbar(flags, bk, g4, ++bc);
        {   // stage owner 8 rows (h cols)
            short8 tv;
            int row = tid >> 6, c16 = tid & 63;
            ldg16_sc(&tv, xh + (size_t)(bk * 8 + row) * 576 + c16 * 8);
            waitv0();
            __builtin_amdgcn_sched_barrier(0);
            *(short8*)&Ald[(ntile * 8 + row) * 584 + c16 * 8] = tv;
        }
        __syncthreads();
        do_head(t);
        if (t < 255) do_uh();
        __syncthreads();
        if (t < 255) {
            // issue 24 remaining rows; hide latency under attention
            short8 s24[3];
#pragma unroll
            for (int q = 0; q < 3; ++q) {
                int cid = tid + q * 512;          // 1536 chunks
                int r24 = cid >> 6, c16 = cid & 63;
                int lr = (r24 < ntile * 8) ? r24 : r24 + 8;
                ldg16_sc(&s24[q], xh + (size_t)(mtile * 32 + lr) * 576 + c16 * 8);
            }
            do_attn(t + 1);
            waitv0();
            __builtin_amdgcn_sched_barrier(0);
#pragma unroll
            for (int q = 0; q < 3; ++q) {
                int cid = tid + q * 512;
                int r24 = cid >> 6, c16 = cid & 63;
                int lr = (r24 < ntile * 8) ? r24 : r24 + 8;
                *(short8*)&Ald[lr * 584 + c16 * 8] = s24[q];
            }
            gbar(flags, bk, g4, ++bc);
            if (tid < 256) {   // stage tail cols 512:576 (x/ctx_{t+1})
                short8 tv;
                int row = tid >> 3, c16 = tid & 7;
                ldg16_sc(&tv, xh + (size_t)(mtile * 32 + row) * 576 + 512 + c16 * 8);
                waitv0();
                __builtin_amdgcn_sched_barrier(0);
                *(short8*)&Ald[row * 584 + 512 + c16 * 8] = tv;
            }
            __syncthreads();
        }
    }
}

extern "C" void kernel_launch(void* const* d_in, const int* in_sizes, int n_in,
                              void* d_out, int out_size, void* d_ws, size_t ws_size,
                              hipStream_t stream) {
    const float* img   = (const float*)d_in[0];
    const float* label = (const float*)d_in[1];
    const float* Ww    = (const float*)d_in[2];
    const float* Wb    = (const float*)d_in[3];
    const float* Uw    = (const float*)d_in[4];
    const float* Ub    = (const float*)d_in[5];
    const float* vw    = (const float*)d_in[6];
    // d_in[7] = vb (cancels in softmax)
    const float* betaw = (const float*)d_in[8];
    const float* betab = (const float*)d_in[9];
    const float* ihw   = (const float*)d_in[10];
    const float* ihb   = (const float*)d_in[11];
    const float* icw   = (const float*)d_in[12];
    const float* icb   = (const float*)d_in[13];
    const float* Wih   = (const float*)d_in[14];
    const float* Whh   = (const float*)d_in[15];
    const float* bih   = (const float*)d_in[16];
    const float* bhh   = (const float*)d_in[17];
    const float* ow    = (const float*)d_in[18];
    const float* ob    = (const float*)d_in[19];

    char* ws = (char*)d_ws;
    unsigned short* xh       = (unsigned short*)(ws + OFF_XH);
    float*          c0       = (float*)(ws + OFF_C0);
    unsigned short* parts_bf = (unsigned short*)(ws + OFF_PARTS);
    unsigned short* Wbig     = (unsigned short*)(ws + OFF_WBIG);
    unsigned short* Wsmall   = (unsigned short*)(ws + OFF_WSMALL);
    unsigned short* Ww2      = (unsigned short*)(ws + OFF_WW2);
    float*          bias     = (float*)(ws + OFF_BIAS);
    float*          avg      = (float*)(ws + OFF_AVG);
    int*            flags    = (int*)(ws + OFF_FLAGS);

    float* out_logits = (float*)d_out;
    float* out_alpha  = out_logits + (size_t)2048 * 256 * 12;

    k_init<<<32, 256, 0, stream>>>(flags);
    k_avg<<<512, 256, 0, stream>>>(img, avg);
    k_prep<<<2048, 256, 0, stream>>>(Whh, Wih, Uw, betaw, Ww, bih, bhh, Wbig, Wsmall, Ww2, bias);
    k_h0c0<<<256, 512, 0, stream>>>(avg, ihw, ihb, icw, icb, xh, c0);
    k_parts<<<2048, 256, 0, stream>>>(img, parts_bf);

    k_scan<<<256, 512, 0, stream>>>(xh, c0, parts_bf, Wsmall, Wbig, Ww2, bias,
                                    Ub, betab, Wb, vw, label, ow, ob,
                                    out_alpha, out_logits, flags);
}

// Round 11
// 14695.958 us; speedup vs baseline: 2.4152x; 1.0358x over previous
//
#include <hip/hip_runtime.h>
#include <hip/hip_bf16.h>

// Persistent tile-owner decoder v3. G=64 groups x P=4 blocks, 256 blocks x 512thr,
// 1 block/CU. Block bk: mtile=bk>>2 (32 rows), ntile=bk&3 (512 perm-cols = 128
// j-cols). Groups never communicate; barrier = 4 flags via L3 (sc0 sc1, no fences).
// R10 post-mortem: h2 was 1024 scattered 8B sc-stores/block/step -> partial-line
// L3 RMW + slow vmcnt drain at gbar (~40us/step hidden). v3 bounces h2 through
// LDS and stores 512 coalesced 16B sc-stores instead.

typedef __attribute__((ext_vector_type(8))) short short8;
typedef __attribute__((ext_vector_type(4))) float floatx4;
typedef __attribute__((ext_vector_type(2))) unsigned int uint2v;

#define DEV static __device__ __forceinline__
#define C2LE 2.885390082f    // 2*log2(e)
#define LOG2E 1.4426950409f
#define LN2 0.6931471806f

DEV unsigned short f2bf(float f) {
    unsigned int u = __float_as_uint(f);
    unsigned int r = (u + 0x7FFFu + ((u >> 16) & 1u)) >> 16;
    return (unsigned short)r;
}
DEV float bf2f(unsigned short u) { return __uint_as_float(((unsigned int)u) << 16); }
DEV float rcp_f(float x) { float r; asm("v_rcp_f32 %0, %1" : "=v"(r) : "v"(x)); return r; }
DEV float tanh_f(float x) { return 1.f - 2.f * rcp_f(1.f + exp2f(x * C2LE)); }
DEV float sigm(float x) { return rcp_f(1.f + exp2f(-x * LOG2E)); }

// ---- L3-coherent (L1+L2 bypass) helpers [R9/R10-proven] ----
DEV void ldg16_sc(short8* d, const unsigned short* p) {
    asm volatile("global_load_dwordx4 %0, %1, off sc0 sc1" : "=v"(*d) : "v"(p));
}
DEV void stg16_sc(unsigned short* p, short8 v) {
    asm volatile("global_store_dwordx4 %0, %1, off sc0 sc1" :: "v"(p), "v"(v) : "memory");
}
DEV void stg8_sc(unsigned short* p, uint2v v) {
    asm volatile("global_store_dwordx2 %0, %1, off sc0 sc1" :: "v"(p), "v"(v) : "memory");
}
DEV void st_flag(int* p, int v) {
    asm volatile("global_store_dword %0, %1, off sc0 sc1" :: "v"(p), "v"(v) : "memory");
}
DEV int ld_flag(const int* p) {
    int v;
    asm volatile("global_load_dword %0, %1, off sc0 sc1\n\ts_waitcnt vmcnt(0)"
                 : "=v"(v) : "v"(p) : "memory");
    return v;
}
DEV void waitv0() { asm volatile("s_waitcnt vmcnt(0)" ::: "memory"); }

// ---------------- workspace layout (bytes) ----------------
#define OFF_XH     ((size_t)0)          // bf16 [2048][576]: h|x|ctx|pad0(20)
#define OFF_C0     ((size_t)2359296)    // f32 [2048][512]
#define OFF_PARTS  ((size_t)6553600)    // bf16 [2048][64][32]
#define OFF_WBIG   ((size_t)14942208)   // bf16 [2048][576], perm p=4j+g <- orig g*512+j
#define OFF_WSMALL ((size_t)17301504)   // bf16 [160][512]
#define OFF_WW2    ((size_t)17465344)   // bf16 [128][32] = C2LE*Ww
#define OFF_BIAS   ((size_t)17473536)   // f32 [2048]
#define OFF_AVG    ((size_t)17481728)   // f32 [2048][64]
#define OFF_FLAGS  ((size_t)18006016)   // int [256*32]

// group barrier (P=4), per-block flag via L3, no fences
DEV void gbar(int* flags, int bk, int g4, int step) {
    waitv0();
    __syncthreads();
    if (threadIdx.x < 64) {
        int lane = threadIdx.x;
        if (lane == 0) st_flag(flags + bk * 32, step);
        for (;;) {
            int v = step;
            if (lane < 4) v = ld_flag(flags + (g4 + lane) * 32);
            if (__all(v >= step)) break;
            __builtin_amdgcn_s_sleep(1);
        }
    }
    __syncthreads();
}

__global__ void k_init(int* flags) {
    int i = blockIdx.x * 256 + threadIdx.x;
    if (i < 256 * 32) flags[i] = 0;
}

__global__ void k_avg(const float* __restrict__ img, float* __restrict__ avg) {
    int idx = blockIdx.x * 256 + threadIdx.x;
    int b = idx >> 6, p = idx & 63;
    const float* base = img + (size_t)b * 2048 + p;
    float s = 0.f;
#pragma unroll
    for (int k = 0; k < 32; ++k) s += base[k * 64];
    avg[idx] = s * (1.f / 32.f);
}

__global__ void k_prep(const float* __restrict__ Whh, const float* __restrict__ Wih,
                       const float* __restrict__ Uw, const float* __restrict__ betaw,
                       const float* __restrict__ Ww, const float* __restrict__ bih,
                       const float* __restrict__ bhh,
                       unsigned short* __restrict__ Wbig, unsigned short* __restrict__ Wsmall,
                       unsigned short* __restrict__ Ww2, float* __restrict__ bias_cat) {
    int p = blockIdx.x, tid = threadIdx.x;
    int g = p & 3, j = p >> 2, orig = g * 512 + j;
    for (int k = tid; k < 576; k += 256) {
        float v = 0.f;
        if (k < 512) v = Whh[(size_t)orig * 512 + k];
        else if (k < 556) v = Wih[(size_t)orig * 44 + (k - 512)];
        Wbig[(size_t)p * 576 + k] = f2bf(v);
    }
    if (p < 160) {
        for (int k = tid; k < 512; k += 256) {
            float v = (p < 128) ? Uw[(size_t)p * 512 + k] : betaw[(size_t)(p - 128) * 512 + k];
            Wsmall[(size_t)p * 512 + k] = f2bf(v);
        }
    }
    if (p < 128 && tid < 32) Ww2[p * 32 + tid] = f2bf(C2LE * Ww[p * 32 + tid]);
    if (tid == 0) bias_cat[orig] = bih[orig] + bhh[orig];
}

__global__ __launch_bounds__(512) void k_h0c0(const float* __restrict__ avg,
                                              const float* __restrict__ ihw, const float* __restrict__ ihb,
                                              const float* __restrict__ icw, const float* __restrict__ icb,
                                              unsigned short* __restrict__ xh, float* __restrict__ c0) {
    __shared__ float avg_s[8][64];
    int b0 = blockIdx.x * 8, tid = threadIdx.x;
    for (int i = tid; i < 8 * 64; i += 512) avg_s[i >> 6][i & 63] = avg[b0 * 64 + i];
    __syncthreads();
    int j = tid;
    float w0[64];
#pragma unroll
    for (int p4 = 0; p4 < 16; ++p4) {
        float4 v = ((const float4*)(ihw + j * 64))[p4];
        w0[p4 * 4 + 0] = v.x; w0[p4 * 4 + 1] = v.y; w0[p4 * 4 + 2] = v.z; w0[p4 * 4 + 3] = v.w;
    }
    float bh = ihb[j];
#pragma unroll
    for (int bb = 0; bb < 8; ++bb) {
        float s = bh;
#pragma unroll
        for (int p = 0; p < 64; ++p) s += w0[p] * avg_s[bb][p];
        xh[(size_t)(b0 + bb) * 576 + j] = f2bf(tanh_f(s));
        if (j < 20) xh[(size_t)(b0 + bb) * 576 + 556 + j] = 0;
    }
#pragma unroll
    for (int p4 = 0; p4 < 16; ++p4) {
        float4 v = ((const float4*)(icw + j * 64))[p4];
        w0[p4 * 4 + 0] = v.x; w0[p4 * 4 + 1] = v.y; w0[p4 * 4 + 2] = v.z; w0[p4 * 4 + 3] = v.w;
    }
    float bc = icb[j];
#pragma unroll
    for (int bb = 0; bb < 8; ++bb) {
        float s = bc;
#pragma unroll
        for (int p = 0; p < 64; ++p) s += w0[p] * avg_s[bb][p];
        c0[(size_t)(b0 + bb) * 512 + j] = tanh_f(s);
    }
}

// parts_bf[b][p][k] = bf16(img[b][k][p])
__global__ __launch_bounds__(256) void k_parts(const float* __restrict__ img,
                                               unsigned short* __restrict__ parts_bf) {
    __shared__ float pl[64][33];
    int b = blockIdx.x, tid = threadIdx.x;
    const float* ib = img + (size_t)b * 2048;
    for (int i = tid; i < 2048; i += 256) pl[i & 63][i >> 6] = ib[i];
    __syncthreads();
    for (int i = tid; i < 2048; i += 256)
        parts_bf[(size_t)b * 2048 + i] = f2bf(pl[i >> 5][i & 31]);
}

__global__ __launch_bounds__(512, 2) void k_scan(
    unsigned short* __restrict__ xh,
    const float* __restrict__ c0,
    const unsigned short* __restrict__ parts_bf,
    const unsigned short* __restrict__ Wsmall, const unsigned short* __restrict__ Wbig,
    const unsigned short* __restrict__ Ww2, const float* __restrict__ bias_cat,
    const float* __restrict__ Ub, const float* __restrict__ betab, const float* __restrict__ Wb,
    const float* __restrict__ vw,
    const float* __restrict__ label, const float* __restrict__ ow, const float* __restrict__ ob,
    float* __restrict__ out_alpha, float* __restrict__ out_logits,
    int* __restrict__ flags)
{
    __shared__ unsigned short Ald[32 * 584];      // 36.5 KB A-tile
    __shared__ unsigned short parts_l[8][2304];   // 36.9 KB
    __shared__ unsigned short ow_l[12][512];      // 12.3 KB
    __shared__ unsigned short h2scr[32][128];     // 8 KB  h2 bounce (coalesce stores)
    __shared__ float uh_l[8][160];                // 5 KB
    __shared__ float al_l[8][64];                 // 2 KB
    __shared__ float bias_l[512];                 // 2 KB
    __shared__ unsigned short xscr[8][48];
    __shared__ float vw2_l[128];
    __shared__ float obl[12];

    const int tid = threadIdx.x, w = tid >> 6, lane = tid & 63;
    const int bk = blockIdx.x;
    const int mtile = bk >> 2, ntile = bk & 3;
    const int g4 = bk & ~3;
    const int wm = w >> 2, wn = w & 3;

    // ---- one-time LDS staging ----
    if (tid < 128) vw2_l[tid] = -2.f * vw[tid];
    if (tid < 12) obl[tid] = ob[tid];
    {
        int g = tid >> 7, jl = tid & 127;
        bias_l[tid] = bias_cat[g * 512 + ntile * 128 + jl];
    }
    for (int i = tid; i < 12 * 512; i += 512) ow_l[i >> 9][i & 511] = f2bf(ow[i]);
    {
        int row = tid >> 6, p = tid & 63;
        const short8* src = (const short8*)(parts_bf + (size_t)(bk * 8 + row) * 2048 + p * 32);
        short8* dst = (short8*)&parts_l[row][p * 36];
        dst[0] = src[0]; dst[1] = src[1]; dst[2] = src[2]; dst[3] = src[3];
    }
    // c registers: cell (b, j) = (mtile*32 + wm*16 + (lane>>4)*4 + r,
    //                             ntile*128 + wn*32 + nf*4 + (lane&3)); creg[nf*4+r]
    float creg[32];
#pragma unroll
    for (int nf = 0; nf < 8; ++nf)
#pragma unroll
        for (int r = 0; r < 4; ++r) {
            int b = mtile * 32 + wm * 16 + (lane >> 4) * 4 + r;
            int j = ntile * 128 + wn * 32 + nf * 4 + (lane & 3);
            creg[nf * 4 + r] = c0[(size_t)b * 512 + j];
        }
    // prologue stage: all 32 rows, h cols (0:512)
    {
        short8 tv[4];
#pragma unroll
        for (int q = 0; q < 4; ++q) {
            int cid = tid + q * 512;
            int row = cid >> 6, c16 = cid & 63;
            ldg16_sc(&tv[q], xh + (size_t)(mtile * 32 + row) * 576 + c16 * 8);
        }
        waitv0();
        __builtin_amdgcn_sched_barrier(0);
#pragma unroll
        for (int q = 0; q < 4; ++q) {
            int cid = tid + q * 512;
            int row = cid >> 6, c16 = cid & 63;
            *(short8*)&Ald[row * 584 + c16 * 8] = tv[q];
        }
    }
    __syncthreads();
    float vwsum = 0.f;
#pragma unroll
    for (int d = 0; d < 128; ++d) vwsum += vw2_l[d];
    vwsum *= -0.5f;

    // ---- Uh GEMM: uh_l[8][160] = owner h @ Wsmall^T (waves 0..4) ----
    auto do_uh = [&]() {
        if (w < 5) {
            const unsigned short* Bp = Wsmall + (size_t)(w * 32 + (lane & 15)) * 512 + (lane >> 4) * 8;
            const unsigned short* Ab = &Ald[(ntile * 8 + (lane & 7)) * 584 + (lane >> 4) * 8];
            floatx4 u0 = {}, u1 = {};
#pragma unroll 4
            for (int k0 = 0; k0 < 512; k0 += 32) {
                short8 a = *(const short8*)(Ab + k0);
                u0 = __builtin_amdgcn_mfma_f32_16x16x32_bf16(a, *(const short8*)(Bp + k0), u0, 0, 0, 0);
                u1 = __builtin_amdgcn_mfma_f32_16x16x32_bf16(a, *(const short8*)(Bp + 16 * 512 + k0), u1, 0, 0, 0);
            }
            int r0 = (lane >> 4) * 4, cc = lane & 15;
            if (r0 < 8) {
#pragma unroll
                for (int q = 0; q < 2; ++q) {
                    int n = w * 32 + q * 16 + cc;
#pragma unroll
                    for (int r = 0; r < 4; ++r) {
                        float val = (q ? u1[r] : u0[r]);
                        uh_l[r0 + r][n] = (n < 128) ? C2LE * (val + Ub[n] + Wb[n])
                                                    : (val + betab[n - 128]);
                    }
                }
            }
        }
    };

    // ---- output head: logits[tt] from owner rows (Ald) ----
    auto do_head = [&](int tt) {
        int b = bk * 8 + w;
        short8 hv = *(const short8*)&Ald[(ntile * 8 + w) * 584 + lane * 8];
        float hf[8];
#pragma unroll
        for (int j = 0; j < 8; ++j) hf[j] = bf2f((unsigned short)hv[j]);
        float ov[12];
#pragma unroll
        for (int v = 0; v < 12; ++v) {
            short8 wv = *(const short8*)&ow_l[v][lane * 8];
            float p = 0.f;
#pragma unroll
            for (int j = 0; j < 8; ++j) p += hf[j] * bf2f((unsigned short)wv[j]);
#pragma unroll
            for (int o = 32; o; o >>= 1) p += __shfl_xor(p, o);
            ov[v] = p + obl[v];
        }
        float mx = ov[0];
#pragma unroll
        for (int v = 1; v < 12; ++v) mx = fmaxf(mx, ov[v]);
        float ss = 0.f;
#pragma unroll
        for (int v = 0; v < 12; ++v) ss += exp2f((ov[v] - mx) * LOG2E);
        float lse = mx + log2f(ss) * LN2;
#pragma unroll
        for (int v = 0; v < 12; ++v)
            if (lane == v) out_logits[((size_t)b * 256 + tt) * 12 + v] = ov[v] - lse;
    };

    // ---- attention(tt): score/softmax/ctx; packed x/ctx sc-stores ----
    auto do_attn = [&](int tt) {
        int b = bk * 8 + w;
        short8 pa[4];
#pragma unroll
        for (int mt = 0; mt < 4; ++mt)
            pa[mt] = *(const short8*)&parts_l[w][(mt * 16 + (lane & 15)) * 36 + (lane >> 4) * 8];
        float sc[4][4] = {};
#pragma unroll
        for (int nt = 0; nt < 8; ++nt) {
            short8 wwf = *(const short8*)(Ww2 + (size_t)((lane & 15) + 16 * nt) * 32 + (lane >> 4) * 8);
            int d = nt * 16 + (lane & 15);
            float ud = uh_l[w][d];
            float v2 = vw2_l[d];
#pragma unroll
            for (int mt = 0; mt < 4; ++mt) {
                floatx4 z = {};
                floatx4 wsa = __builtin_amdgcn_mfma_f32_16x16x32_bf16(pa[mt], wwf, z, 0, 0, 0);
#pragma unroll
                for (int r = 0; r < 4; ++r)
                    sc[mt][r] += v2 * rcp_f(1.f + exp2f(wsa[r] + ud));
            }
        }
        float mx = -1e30f;
#pragma unroll
        for (int mt = 0; mt < 4; ++mt)
#pragma unroll
            for (int r = 0; r < 4; ++r) {
                float s = sc[mt][r];
                s += __shfl_xor(s, 1); s += __shfl_xor(s, 2);
                s += __shfl_xor(s, 4); s += __shfl_xor(s, 8);
                s += vwsum;
                sc[mt][r] = s;
                mx = fmaxf(mx, s);
            }
        mx = fmaxf(mx, __shfl_xor(mx, 16));
        mx = fmaxf(mx, __shfl_xor(mx, 32));
        float ssum = 0.f;
        float av[4][4];
#pragma unroll
        for (int mt = 0; mt < 4; ++mt)
#pragma unroll
            for (int r = 0; r < 4; ++r) {
                av[mt][r] = exp2f((sc[mt][r] - mx) * LOG2E);
                ssum += av[mt][r];
            }
        ssum += __shfl_xor(ssum, 16);
        ssum += __shfl_xor(ssum, 32);
        float rs = rcp_f(ssum);
#pragma unroll
        for (int mt = 0; mt < 4; ++mt) {
            if ((lane & 15) == mt) {
                float4 fv = make_float4(av[mt][0] * rs, av[mt][1] * rs, av[mt][2] * rs, av[mt][3] * rs);
                int p0 = mt * 16 + (lane >> 4) * 4;
                *(float4*)&out_alpha[((size_t)tt * 2048 + b) * 64 + p0] = fv;
                *(float4*)&al_l[w][p0] = fv;
            }
        }
        int k = lane & 31, half = lane >> 5;
        float cp = 0.f;
#pragma unroll
        for (int p = 0; p < 32; ++p) {
            int pp = half * 32 + p;
            cp += al_l[w][pp] * bf2f(parts_l[w][pp * 36 + k]);
        }
        cp += __shfl_xor(cp, 32);
        if (half == 0) xscr[w][12 + k] = f2bf(cp * sigm(uh_l[w][128 + k]));
        if (lane < 12) xscr[w][lane] = f2bf(label[((size_t)b * 256 + tt) * 12 + lane]);
        if (lane < 11) {
            uint2v v = *(const uint2v*)&xscr[w][lane * 4];
            stg8_sc(xh + (size_t)b * 576 + 512 + lane * 4, v);
        }
    };

    // ---- phase1: gates GEMM (A LDS x B L2) + fused cell; h2 via LDS bounce ----
    auto phase1 = [&]() {
        const unsigned short* Bp = Wbig + (size_t)(ntile * 512 + wn * 128 + (lane & 15)) * 576 + (lane >> 4) * 8;
        const unsigned short* Ab = &Ald[(wm * 16 + (lane & 15)) * 584 + (lane >> 4) * 8];
        floatx4 acc[8] = {};
#pragma unroll 2
        for (int kk = 0; kk < 18; ++kk) {
            int k0 = kk * 32;
            short8 a = *(const short8*)(Ab + k0);
#pragma unroll
            for (int nf = 0; nf < 8; ++nf) {
                short8 bv = *(const short8*)(Bp + (size_t)nf * 9216 + k0);
                acc[nf] = __builtin_amdgcn_mfma_f32_16x16x32_bf16(a, bv, acc[nf], 0, 0, 0);
            }
        }
        int base = (lane & 48) | ((lane & 3) * 4);
#pragma unroll
        for (int nf = 0; nf < 8; ++nf) {
            int jl = wn * 32 + nf * 4 + (lane & 3);
            float bi = bias_l[jl], bfv = bias_l[128 + jl], bg = bias_l[256 + jl], bo = bias_l[384 + jl];
#pragma unroll
            for (int r = 0; r < 4; ++r) {
                float x = acc[nf][r];
                float g0 = __shfl(x, base + 0);
                float g1 = __shfl(x, base + 1);
                float g2 = __shfl(x, base + 2);
                float g3 = __shfl(x, base + 3);
                int ci = nf * 4 + r;
                float c2 = sigm(g1 + bfv) * creg[ci] + sigm(g0 + bi) * tanh_f(g2 + bg);
                creg[ci] = c2;
                float h2 = sigm(g3 + bo) * tanh_f(c2);
                if (((lane >> 2) & 3) == 0) {
                    int row = wm * 16 + (lane >> 4) * 4 + r;   // local 0..31
                    h2scr[row][wn * 32 + nf * 4 + (lane & 3)] = f2bf(h2);
                }
            }
        }
        __syncthreads();   // h2scr complete
        // coalesced h2 store: 512 thr x 16B = 32 rows x 128 cols
        {
            int row = tid >> 4, seg = tid & 15;
            short8 v = *(const short8*)&h2scr[row][seg * 8];
            stg16_sc(xh + (size_t)(mtile * 32 + row) * 576 + ntile * 128 + seg * 8, v);
        }
    };

    // ---- prologue: Uh(0) + attention(0) on h0 ----
    do_uh();
    __syncthreads();
    do_attn(0);
    int bc = 0;
    gbar(flags, bk, g4, ++bc);
    if (tid < 256) {   // stage tail (x0/ctx0 + zeros), cols 512:576
        short8 tv;
        int row = tid >> 3, c16 = tid & 7;
        ldg16_sc(&tv, xh + (size_t)(mtile * 32 + row) * 576 + 512 + c16 * 8);
        waitv0();
        __builtin_amdgcn_sched_barrier(0);
        *(short8*)&Ald[row * 584 + 512 + c16 * 8] = tv;
    }
    __syncthreads();

    for (int t = 0; t < 256; ++t) {
        phase1();
        gbar(flags, bk, g4, ++bc);
        {   // stage owner 8 rows (h cols)
            short8 tv;
            int row = tid >> 6, c16 = tid & 63;
            ldg16_sc(&tv, xh + (size_t)(bk * 8 + row) * 576 + c16 * 8);
            waitv0();
            __builtin_amdgcn_sched_barrier(0);
            *(short8*)&Ald[(ntile * 8 + row) * 584 + c16 * 8] = tv;
        }
        __syncthreads();
        do_head(t);
        if (t < 255) do_uh();
        __syncthreads();
        if (t < 255) {
            // issue 24 remaining rows; hide latency under attention
            short8 s24[3];
#pragma unroll
            for (int q = 0; q < 3; ++q) {
                int cid = tid + q * 512;
                int r24 = cid >> 6, c16 = cid & 63;
                int lr = (r24 < ntile * 8) ? r24 : r24 + 8;
                ldg16_sc(&s24[q], xh + (size_t)(mtile * 32 + lr) * 576 + c16 * 8);
            }
            do_attn(t + 1);
            waitv0();
            __builtin_amdgcn_sched_barrier(0);
#pragma unroll
            for (int q = 0; q < 3; ++q) {
                int cid = tid + q * 512;
                int r24 = cid >> 6, c16 = cid & 63;
                int lr = (r24 < ntile * 8) ? r24 : r24 + 8;
                *(short8*)&Ald[lr * 584 + c16 * 8] = s24[q];
            }
            gbar(flags, bk, g4, ++bc);
            if (tid < 256) {   // stage tail cols 512:576 (x/ctx_{t+1})
                short8 tv;
                int row = tid >> 3, c16 = tid & 7;
                ldg16_sc(&tv, xh + (size_t)(mtile * 32 + row) * 576 + 512 + c16 * 8);
                waitv0();
                __builtin_amdgcn_sched_barrier(0);
                *(short8*)&Ald[row * 584 + 512 + c16 * 8] = tv;
            }
            __syncthreads();
        }
    }
}

extern "C" void kernel_launch(void* const* d_in, const int* in_sizes, int n_in,
                              void* d_out, int out_size, void* d_ws, size_t ws_size,
                              hipStream_t stream) {
    const float* img   = (const float*)d_in[0];
    const float* label = (const float*)d_in[1];
    const float* Ww    = (const float*)d_in[2];
    const float* Wb    = (const float*)d_in[3];
    const float* Uw    = (const float*)d_in[4];
    const float* Ub    = (const float*)d_in[5];
    const float* vw    = (const float*)d_in[6];
    // d_in[7] = vb (cancels in softmax)
    const float* betaw = (const float*)d_in[8];
    const float* betab = (const float*)d_in[9];
    const float* ihw   = (const float*)d_in[10];
    const float* ihb   = (const float*)d_in[11];
    const float* icw   = (const float*)d_in[12];
    const float* icb   = (const float*)d_in[13];
    const float* Wih   = (const float*)d_in[14];
    const float* Whh   = (const float*)d_in[15];
    const float* bih   = (const float*)d_in[16];
    const float* bhh   = (const float*)d_in[17];
    const float* ow    = (const float*)d_in[18];
    const float* ob    = (const float*)d_in[19];

    char* ws = (char*)d_ws;
    unsigned short* xh       = (unsigned short*)(ws + OFF_XH);
    float*          c0       = (float*)(ws + OFF_C0);
    unsigned short* parts_bf = (unsigned short*)(ws + OFF_PARTS);
    unsigned short* Wbig     = (unsigned short*)(ws + OFF_WBIG);
    unsigned short* Wsmall   = (unsigned short*)(ws + OFF_WSMALL);
    unsigned short* Ww2      = (unsigned short*)(ws + OFF_WW2);
    float*          bias     = (float*)(ws + OFF_BIAS);
    float*          avg      = (float*)(ws + OFF_AVG);
    int*            flags    = (int*)(ws + OFF_FLAGS);

    float* out_logits = (float*)d_out;
    float* out_alpha  = out_logits + (size_t)2048 * 256 * 12;

    k_init<<<32, 256, 0, stream>>>(flags);
    k_avg<<<512, 256, 0, stream>>>(img, avg);
    k_prep<<<2048, 256, 0, stream>>>(Whh, Wih, Uw, betaw, Ww, bih, bhh, Wbig, Wsmall, Ww2, bias);
    k_h0c0<<<256, 512, 0, stream>>>(avg, ihw, ihb, icw, icb, xh, c0);
    k_parts<<<2048, 256, 0, stream>>>(img, parts_bf);

    k_scan<<<256, 512, 0, stream>>>(xh, c0, parts_bf, Wsmall, Wbig, Ww2, bias,
                                    Ub, betab, Wb, vw, label, ow, ob,
                                    out_alpha, out_logits, flags);
}

// Round 12
// 14272.614 us; speedup vs baseline: 2.4868x; 1.0297x over previous
//
#include <hip/hip_runtime.h>
#include <hip/hip_bf16.h>

// Persistent tile-owner decoder v4: latency-hiding restructure of R11.
// G=64 groups x P=4 blocks, 256 blocks x 512thr, 1 block/CU.
// Block bk: mtile=bk>>2 (32 rows), ntile=bk&3 (128 j-cols). Groups isolated.
// R11 post-mortem: ~57us/step with GPU 70% idle across R9-R11 despite traffic
// dropping 10x -> cost = # of serial latency segments (3 gbars + 3 blocked
// stages). v4: split gates GEMM K=[0:512 | 512:576]; x/ctx published at end of
// prev iteration, the 4-5us K=0:512 GEMM runs BEFORE gbar_x so publish/skew
// latency hides under compute; owner-row stage merged into the 32-row stage.
// 2 gbars/step (one cold, one hot), 2 stages.

typedef __attribute__((ext_vector_type(8))) short short8;
typedef __attribute__((ext_vector_type(4))) float floatx4;
typedef __attribute__((ext_vector_type(2))) unsigned int uint2v;

#define DEV static __device__ __forceinline__
#define C2LE 2.885390082f    // 2*log2(e)
#define LOG2E 1.4426950409f
#define LN2 0.6931471806f

DEV unsigned short f2bf(float f) {
    unsigned int u = __float_as_uint(f);
    unsigned int r = (u + 0x7FFFu + ((u >> 16) & 1u)) >> 16;
    return (unsigned short)r;
}
DEV float bf2f(unsigned short u) { return __uint_as_float(((unsigned int)u) << 16); }
DEV float rcp_f(float x) { float r; asm("v_rcp_f32 %0, %1" : "=v"(r) : "v"(x)); return r; }
DEV float tanh_f(float x) { return 1.f - 2.f * rcp_f(1.f + exp2f(x * C2LE)); }
DEV float sigm(float x) { return rcp_f(1.f + exp2f(-x * LOG2E)); }

// ---- L3-coherent (L1+L2 bypass) helpers [R9-R11 proven] ----
DEV void ldg16_sc(short8* d, const unsigned short* p) {
    asm volatile("global_load_dwordx4 %0, %1, off sc0 sc1" : "=v"(*d) : "v"(p));
}
DEV void stg16_sc(unsigned short* p, short8 v) {
    asm volatile("global_store_dwordx4 %0, %1, off sc0 sc1" :: "v"(p), "v"(v) : "memory");
}
DEV void stg8_sc(unsigned short* p, uint2v v) {
    asm volatile("global_store_dwordx2 %0, %1, off sc0 sc1" :: "v"(p), "v"(v) : "memory");
}
DEV void st_flag(int* p, int v) {
    asm volatile("global_store_dword %0, %1, off sc0 sc1" :: "v"(p), "v"(v) : "memory");
}
DEV int ld_flag(const int* p) {
    int v;
    asm volatile("global_load_dword %0, %1, off sc0 sc1\n\ts_waitcnt vmcnt(0)"
                 : "=v"(v) : "v"(p) : "memory");
    return v;
}
DEV void waitv0() { asm volatile("s_waitcnt vmcnt(0)" ::: "memory"); }

// ---------------- workspace layout (bytes) ----------------
#define OFF_XH     ((size_t)0)          // bf16 [2048][576]: h|x|ctx|pad0(20)
#define OFF_C0     ((size_t)2359296)    // f32 [2048][512]
#define OFF_PARTS  ((size_t)6553600)    // bf16 [2048][64][32]
#define OFF_WBIG   ((size_t)14942208)   // bf16 [2048][576], perm p=4j+g <- orig g*512+j
#define OFF_WSMALL ((size_t)17301504)   // bf16 [160][512]
#define OFF_WW2    ((size_t)17465344)   // bf16 [128][32] = C2LE*Ww
#define OFF_BIAS   ((size_t)17473536)   // f32 [2048]
#define OFF_AVG    ((size_t)17481728)   // f32 [2048][64]
#define OFF_FLAGS  ((size_t)18006016)   // int [256*32]

// group barrier (P=4), per-block flag via L3, no fences
DEV void gbar(int* flags, int bk, int g4, int step) {
    waitv0();
    __syncthreads();
    if (threadIdx.x < 64) {
        int lane = threadIdx.x;
        if (lane == 0) st_flag(flags + bk * 32, step);
        for (;;) {
            int v = step;
            if (lane < 4) v = ld_flag(flags + (g4 + lane) * 32);
            if (__all(v >= step)) break;
            __builtin_amdgcn_s_sleep(1);
        }
    }
    __syncthreads();
}

__global__ void k_init(int* flags) {
    int i = blockIdx.x * 256 + threadIdx.x;
    if (i < 256 * 32) flags[i] = 0;
}

__global__ void k_avg(const float* __restrict__ img, float* __restrict__ avg) {
    int idx = blockIdx.x * 256 + threadIdx.x;
    int b = idx >> 6, p = idx & 63;
    const float* base = img + (size_t)b * 2048 + p;
    float s = 0.f;
#pragma unroll
    for (int k = 0; k < 32; ++k) s += base[k * 64];
    avg[idx] = s * (1.f / 32.f);
}

__global__ void k_prep(const float* __restrict__ Whh, const float* __restrict__ Wih,
                       const float* __restrict__ Uw, const float* __restrict__ betaw,
                       const float* __restrict__ Ww, const float* __restrict__ bih,
                       const float* __restrict__ bhh,
                       unsigned short* __restrict__ Wbig, unsigned short* __restrict__ Wsmall,
                       unsigned short* __restrict__ Ww2, float* __restrict__ bias_cat) {
    int p = blockIdx.x, tid = threadIdx.x;
    int g = p & 3, j = p >> 2, orig = g * 512 + j;
    for (int k = tid; k < 576; k += 256) {
        float v = 0.f;
        if (k < 512) v = Whh[(size_t)orig * 512 + k];
        else if (k < 556) v = Wih[(size_t)orig * 44 + (k - 512)];
        Wbig[(size_t)p * 576 + k] = f2bf(v);
    }
    if (p < 160) {
        for (int k = tid; k < 512; k += 256) {
            float v = (p < 128) ? Uw[(size_t)p * 512 + k] : betaw[(size_t)(p - 128) * 512 + k];
            Wsmall[(size_t)p * 512 + k] = f2bf(v);
        }
    }
    if (p < 128 && tid < 32) Ww2[p * 32 + tid] = f2bf(C2LE * Ww[p * 32 + tid]);
    if (tid == 0) bias_cat[orig] = bih[orig] + bhh[orig];
}

__global__ __launch_bounds__(512) void k_h0c0(const float* __restrict__ avg,
                                              const float* __restrict__ ihw, const float* __restrict__ ihb,
                                              const float* __restrict__ icw, const float* __restrict__ icb,
                                              unsigned short* __restrict__ xh, float* __restrict__ c0) {
    __shared__ float avg_s[8][64];
    int b0 = blockIdx.x * 8, tid = threadIdx.x;
    for (int i = tid; i < 8 * 64; i += 512) avg_s[i >> 6][i & 63] = avg[b0 * 64 + i];
    __syncthreads();
    int j = tid;
    float w0[64];
#pragma unroll
    for (int p4 = 0; p4 < 16; ++p4) {
        float4 v = ((const float4*)(ihw + j * 64))[p4];
        w0[p4 * 4 + 0] = v.x; w0[p4 * 4 + 1] = v.y; w0[p4 * 4 + 2] = v.z; w0[p4 * 4 + 3] = v.w;
    }
    float bh = ihb[j];
#pragma unroll
    for (int bb = 0; bb < 8; ++bb) {
        float s = bh;
#pragma unroll
        for (int p = 0; p < 64; ++p) s += w0[p] * avg_s[bb][p];
        xh[(size_t)(b0 + bb) * 576 + j] = f2bf(tanh_f(s));
        if (j < 20) xh[(size_t)(b0 + bb) * 576 + 556 + j] = 0;
    }
#pragma unroll
    for (int p4 = 0; p4 < 16; ++p4) {
        float4 v = ((const float4*)(icw + j * 64))[p4];
        w0[p4 * 4 + 0] = v.x; w0[p4 * 4 + 1] = v.y; w0[p4 * 4 + 2] = v.z; w0[p4 * 4 + 3] = v.w;
    }
    float bc = icb[j];
#pragma unroll
    for (int bb = 0; bb < 8; ++bb) {
        float s = bc;
#pragma unroll
        for (int p = 0; p < 64; ++p) s += w0[p] * avg_s[bb][p];
        c0[(size_t)(b0 + bb) * 512 + j] = tanh_f(s);
    }
}

// parts_bf[b][p][k] = bf16(img[b][k][p])
__global__ __launch_bounds__(256) void k_parts(const float* __restrict__ img,
                                               unsigned short* __restrict__ parts_bf) {
    __shared__ float pl[64][33];
    int b = blockIdx.x, tid = threadIdx.x;
    const float* ib = img + (size_t)b * 2048;
    for (int i = tid; i < 2048; i += 256) pl[i & 63][i >> 6] = ib[i];
    __syncthreads();
    for (int i = tid; i < 2048; i += 256)
        parts_bf[(size_t)b * 2048 + i] = f2bf(pl[i >> 5][i & 31]);
}

__global__ __launch_bounds__(512, 2) void k_scan(
    unsigned short* __restrict__ xh,
    const float* __restrict__ c0,
    const unsigned short* __restrict__ parts_bf,
    const unsigned short* __restrict__ Wsmall, const unsigned short* __restrict__ Wbig,
    const unsigned short* __restrict__ Ww2, const float* __restrict__ bias_cat,
    const float* __restrict__ Ub, const float* __restrict__ betab, const float* __restrict__ Wb,
    const float* __restrict__ vw,
    const float* __restrict__ label, const float* __restrict__ ow, const float* __restrict__ ob,
    float* __restrict__ out_alpha, float* __restrict__ out_logits,
    int* __restrict__ flags)
{
    __shared__ unsigned short Ald[32 * 584];
    __shared__ unsigned short parts_l[8][2304];
    __shared__ unsigned short ow_l[12][512];
    __shared__ unsigned short h2scr[32][128];
    __shared__ float uh_l[8][160];
    __shared__ float al_l[8][64];
    __shared__ float bias_l[512];
    __shared__ unsigned short xscr[8][48];
    __shared__ float vw2_l[128];
    __shared__ float obl[12];

    const int tid = threadIdx.x, w = tid >> 6, lane = tid & 63;
    const int bk = blockIdx.x;
    const int mtile = bk >> 2, ntile = bk & 3;
    const int g4 = bk & ~3;
    const int wm = w >> 2, wn = w & 3;

    // ---- one-time LDS staging ----
    if (tid < 128) vw2_l[tid] = -2.f * vw[tid];
    if (tid < 12) obl[tid] = ob[tid];
    {
        int g = tid >> 7, jl = tid & 127;
        bias_l[tid] = bias_cat[g * 512 + ntile * 128 + jl];
    }
    for (int i = tid; i < 12 * 512; i += 512) ow_l[i >> 9][i & 511] = f2bf(ow[i]);
    {
        int row = tid >> 6, p = tid & 63;
        const short8* src = (const short8*)(parts_bf + (size_t)(bk * 8 + row) * 2048 + p * 32);
        short8* dst = (short8*)&parts_l[row][p * 36];
        dst[0] = src[0]; dst[1] = src[1]; dst[2] = src[2]; dst[3] = src[3];
    }
    float creg[32];
#pragma unroll
    for (int nf = 0; nf < 8; ++nf)
#pragma unroll
        for (int r = 0; r < 4; ++r) {
            int b = mtile * 32 + wm * 16 + (lane >> 4) * 4 + r;
            int j = ntile * 128 + wn * 32 + nf * 4 + (lane & 3);
            creg[nf * 4 + r] = c0[(size_t)b * 512 + j];
        }

    floatx4 acc[8];     // persists across gbar_x / tail stage
    float vwsum = 0.f;  // set after LDS sync below

    auto stage32 = [&]() {
        short8 tv[4];
#pragma unroll
        for (int q = 0; q < 4; ++q) {
            int cid = tid + q * 512;
            int row = cid >> 6, c16 = cid & 63;
            ldg16_sc(&tv[q], xh + (size_t)(mtile * 32 + row) * 576 + c16 * 8);
        }
        waitv0();
        __builtin_amdgcn_sched_barrier(0);
#pragma unroll
        for (int q = 0; q < 4; ++q) {
            int cid = tid + q * 512;
            int row = cid >> 6, c16 = cid & 63;
            *(short8*)&Ald[row * 584 + c16 * 8] = tv[q];
        }
    };
    auto stage_tail = [&]() {
        if (tid < 256) {
            short8 tv;
            int row = tid >> 3, c16 = tid & 7;
            ldg16_sc(&tv, xh + (size_t)(mtile * 32 + row) * 576 + 512 + c16 * 8);
            waitv0();
            __builtin_amdgcn_sched_barrier(0);
            *(short8*)&Ald[row * 584 + 512 + c16 * 8] = tv;
        }
    };

    auto do_uh = [&]() {
        if (w < 5) {
            const unsigned short* Bp = Wsmall + (size_t)(w * 32 + (lane & 15)) * 512 + (lane >> 4) * 8;
            const unsigned short* Ab = &Ald[(ntile * 8 + (lane & 7)) * 584 + (lane >> 4) * 8];
            floatx4 u0 = {}, u1 = {};
#pragma unroll 4
            for (int k0 = 0; k0 < 512; k0 += 32) {
                short8 a = *(const short8*)(Ab + k0);
                u0 = __builtin_amdgcn_mfma_f32_16x16x32_bf16(a, *(const short8*)(Bp + k0), u0, 0, 0, 0);
                u1 = __builtin_amdgcn_mfma_f32_16x16x32_bf16(a, *(const short8*)(Bp + 16 * 512 + k0), u1, 0, 0, 0);
            }
            int r0 = (lane >> 4) * 4, cc = lane & 15;
            if (r0 < 8) {
#pragma unroll
                for (int q = 0; q < 2; ++q) {
                    int n = w * 32 + q * 16 + cc;
#pragma unroll
                    for (int r = 0; r < 4; ++r) {
                        float val = (q ? u1[r] : u0[r]);
                        uh_l[r0 + r][n] = (n < 128) ? C2LE * (val + Ub[n] + Wb[n])
                                                    : (val + betab[n - 128]);
                    }
                }
            }
        }
    };

    auto do_head = [&](int tt) {
        int b = bk * 8 + w;
        short8 hv = *(const short8*)&Ald[(ntile * 8 + w) * 584 + lane * 8];
        float hf[8];
#pragma unroll
        for (int j = 0; j < 8; ++j) hf[j] = bf2f((unsigned short)hv[j]);
        float ov[12];
#pragma unroll
        for (int v = 0; v < 12; ++v) {
            short8 wv = *(const short8*)&ow_l[v][lane * 8];
            float p = 0.f;
#pragma unroll
            for (int j = 0; j < 8; ++j) p += hf[j] * bf2f((unsigned short)wv[j]);
#pragma unroll
            for (int o = 32; o; o >>= 1) p += __shfl_xor(p, o);
            ov[v] = p + obl[v];
        }
        float mx = ov[0];
#pragma unroll
        for (int v = 1; v < 12; ++v) mx = fmaxf(mx, ov[v]);
        float ss = 0.f;
#pragma unroll
        for (int v = 0; v < 12; ++v) ss += exp2f((ov[v] - mx) * LOG2E);
        float lse = mx + log2f(ss) * LN2;
#pragma unroll
        for (int v = 0; v < 12; ++v)
            if (lane == v) out_logits[((size_t)b * 256 + tt) * 12 + v] = ov[v] - lse;
    };

    auto do_attn = [&](int tt) {
        int b = bk * 8 + w;
        short8 pa[4];
#pragma unroll
        for (int mt = 0; mt < 4; ++mt)
            pa[mt] = *(const short8*)&parts_l[w][(mt * 16 + (lane & 15)) * 36 + (lane >> 4) * 8];
        float sc[4][4] = {};
#pragma unroll
        for (int nt = 0; nt < 8; ++nt) {
            short8 wwf = *(const short8*)(Ww2 + (size_t)((lane & 15) + 16 * nt) * 32 + (lane >> 4) * 8);
            int d = nt * 16 + (lane & 15);
            float ud = uh_l[w][d];
            float v2 = vw2_l[d];
#pragma unroll
            for (int mt = 0; mt < 4; ++mt) {
                floatx4 z = {};
                floatx4 wsa = __builtin_amdgcn_mfma_f32_16x16x32_bf16(pa[mt], wwf, z, 0, 0, 0);
#pragma unroll
                for (int r = 0; r < 4; ++r)
                    sc[mt][r] += v2 * rcp_f(1.f + exp2f(wsa[r] + ud));
            }
        }
        float mx = -1e30f;
#pragma unroll
        for (int mt = 0; mt < 4; ++mt)
#pragma unroll
            for (int r = 0; r < 4; ++r) {
                float s = sc[mt][r];
                s += __shfl_xor(s, 1); s += __shfl_xor(s, 2);
                s += __shfl_xor(s, 4); s += __shfl_xor(s, 8);
                s += vwsum;
                sc[mt][r] = s;
                mx = fmaxf(mx, s);
            }
        mx = fmaxf(mx, __shfl_xor(mx, 16));
        mx = fmaxf(mx, __shfl_xor(mx, 32));
        float ssum = 0.f;
        float av[4][4];
#pragma unroll
        for (int mt = 0; mt < 4; ++mt)
#pragma unroll
            for (int r = 0; r < 4; ++r) {
                av[mt][r] = exp2f((sc[mt][r] - mx) * LOG2E);
                ssum += av[mt][r];
            }
        ssum += __shfl_xor(ssum, 16);
        ssum += __shfl_xor(ssum, 32);
        float rs = rcp_f(ssum);
#pragma unroll
        for (int mt = 0; mt < 4; ++mt) {
            if ((lane & 15) == mt) {
                float4 fv = make_float4(av[mt][0] * rs, av[mt][1] * rs, av[mt][2] * rs, av[mt][3] * rs);
                int p0 = mt * 16 + (lane >> 4) * 4;
                *(float4*)&out_alpha[((size_t)tt * 2048 + b) * 64 + p0] = fv;
                *(float4*)&al_l[w][p0] = fv;
            }
        }
        int k = lane & 31, half = lane >> 5;
        float cp = 0.f;
#pragma unroll
        for (int p = 0; p < 32; ++p) {
            int pp = half * 32 + p;
            cp += al_l[w][pp] * bf2f(parts_l[w][pp * 36 + k]);
        }
        cp += __shfl_xor(cp, 32);
        if (half == 0) xscr[w][12 + k] = f2bf(cp * sigm(uh_l[w][128 + k]));
        if (lane < 12) xscr[w][lane] = f2bf(label[((size_t)b * 256 + tt) * 12 + lane]);
        if (lane < 11) {
            uint2v v = *(const uint2v*)&xscr[w][lane * 4];
            stg8_sc(xh + (size_t)b * 576 + 512 + lane * 4, v);
        }
    };

    auto gemm_h = [&]() {
        const unsigned short* Bp = Wbig + (size_t)(ntile * 512 + wn * 128 + (lane & 15)) * 576 + (lane >> 4) * 8;
        const unsigned short* Ab = &Ald[(wm * 16 + (lane & 15)) * 584 + (lane >> 4) * 8];
#pragma unroll
        for (int nf = 0; nf < 8; ++nf) acc[nf] = (floatx4){0.f, 0.f, 0.f, 0.f};
#pragma unroll 2
        for (int kk = 0; kk < 16; ++kk) {
            int k0 = kk * 32;
            short8 a = *(const short8*)(Ab + k0);
#pragma unroll
            for (int nf = 0; nf < 8; ++nf) {
                short8 bv = *(const short8*)(Bp + (size_t)nf * 9216 + k0);
                acc[nf] = __builtin_amdgcn_mfma_f32_16x16x32_bf16(a, bv, acc[nf], 0, 0, 0);
            }
        }
    };
    auto gemm_tail_cell = [&]() {
        const unsigned short* Bp = Wbig + (size_t)(ntile * 512 + wn * 128 + (lane & 15)) * 576 + (lane >> 4) * 8;
        const unsigned short* Ab = &Ald[(wm * 16 + (lane & 15)) * 584 + (lane >> 4) * 8];
#pragma unroll
        for (int kk = 16; kk < 18; ++kk) {
            int k0 = kk * 32;
            short8 a = *(const short8*)(Ab + k0);
#pragma unroll
            for (int nf = 0; nf < 8; ++nf) {
                short8 bv = *(const short8*)(Bp + (size_t)nf * 9216 + k0);
                acc[nf] = __builtin_amdgcn_mfma_f32_16x16x32_bf16(a, bv, acc[nf], 0, 0, 0);
            }
        }
        int base = (lane & 48) | ((lane & 3) * 4);
#pragma unroll
        for (int nf = 0; nf < 8; ++nf) {
            int jl = wn * 32 + nf * 4 + (lane & 3);
            float bi = bias_l[jl], bfv = bias_l[128 + jl], bg = bias_l[256 + jl], bo = bias_l[384 + jl];
#pragma unroll
            for (int r = 0; r < 4; ++r) {
                float x = acc[nf][r];
                float g0 = __shfl(x, base + 0);
                float g1 = __shfl(x, base + 1);
                float g2 = __shfl(x, base + 2);
                float g3 = __shfl(x, base + 3);
                int ci = nf * 4 + r;
                float c2 = sigm(g1 + bfv) * creg[ci] + sigm(g0 + bi) * tanh_f(g2 + bg);
                creg[ci] = c2;
                float h2 = sigm(g3 + bo) * tanh_f(c2);
                if (((lane >> 2) & 3) == 0) {
                    int row = wm * 16 + (lane >> 4) * 4 + r;
                    h2scr[row][wn * 32 + nf * 4 + (lane & 3)] = f2bf(h2);
                }
            }
        }
        __syncthreads();
        {
            int row = tid >> 4, seg = tid & 15;
            short8 v = *(const short8*)&h2scr[row][seg * 8];
            stg16_sc(xh + (size_t)(mtile * 32 + row) * 576 + ntile * 128 + seg * 8, v);
        }
    };

    // ---- prologue ----
    stage32();                 // h(0)
    __syncthreads();
    {
        float s = 0.f;
#pragma unroll
        for (int d = 0; d < 128; ++d) s += vw2_l[d];
        vwsum = -0.5f * s;
    }
    do_uh();
    __syncthreads();
    do_attn(0);                // publishes x/ctx(0); first gemm_h hides it

    int bc = 0;
    for (int t = 0; t < 256; ++t) {
        gemm_h();                          // K 0:512 (needs only h in Ald)
        gbar(flags, bk, g4, ++bc);         // x/ctx(t) confirm (cold)
        stage_tail();                      // x/ctx(t) -> Ald
        __syncthreads();
        gemm_tail_cell();                  // K 512:576 + cell + h(t+1) publish
        gbar(flags, bk, g4, ++bc);         // h(t+1) confirm (hot)
        stage32();                         // h(t+1) -> Ald
        __syncthreads();
        do_head(t);                        // logits(t) from h(t+1)
        if (t < 255) {
            do_uh();
            __syncthreads();
            do_attn(t + 1);                // publishes x/ctx(t+1)
        }
    }
}

extern "C" void kernel_launch(void* const* d_in, const int* in_sizes, int n_in,
                              void* d_out, int out_size, void* d_ws, size_t ws_size,
                              hipStream_t stream) {
    const float* img   = (const float*)d_in[0];
    const float* label = (const float*)d_in[1];
    const float* Ww    = (const float*)d_in[2];
    const float* Wb    = (const float*)d_in[3];
    const float* Uw    = (const float*)d_in[4];
    const float* Ub    = (const float*)d_in[5];
    const float* vw    = (const float*)d_in[6];
    // d_in[7] = vb (cancels in softmax)
    const float* betaw = (const float*)d_in[8];
    const float* betab = (const float*)d_in[9];
    const float* ihw   = (const float*)d_in[10];
    const float* ihb   = (const float*)d_in[11];
    const float* icw   = (const float*)d_in[12];
    const float* icb   = (const float*)d_in[13];
    const float* Wih   = (const float*)d_in[14];
    const float* Whh   = (const float*)d_in[15];
    const float* bih   = (const float*)d_in[16];
    const float* bhh   = (const float*)d_in[17];
    const float* ow    = (const float*)d_in[18];
    const float* ob    = (const float*)d_in[19];

    char* ws = (char*)d_ws;
    unsigned short* xh       = (unsigned short*)(ws + OFF_XH);
    float*          c0       = (float*)(ws + OFF_C0);
    unsigned short* parts_bf = (unsigned short*)(ws + OFF_PARTS);
    unsigned short* Wbig     = (unsigned short*)(ws + OFF_WBIG);
    unsigned short* Wsmall   = (unsigned short*)(ws + OFF_WSMALL);
    unsigned short* Ww2      = (unsigned short*)(ws + OFF_WW2);
    float*          bias     = (float*)(ws + OFF_BIAS);
    float*          avg      = (float*)(ws + OFF_AVG);
    int*            flags    = (int*)(ws + OFF_FLAGS);

    float* out_logits = (float*)d_out;
    float* out_alpha  = out_logits + (size_t)2048 * 256 * 12;

    k_init<<<32, 256, 0, stream>>>(flags);
    k_avg<<<512, 256, 0, stream>>>(img, avg);
    k_prep<<<2048, 256, 0, stream>>>(Whh, Wih, Uw, betaw, Ww, bih, bhh, Wbig, Wsmall, Ww2, bias);
    k_h0c0<<<256, 512, 0, stream>>>(avg, ihw, ihb, icw, icb, xh, c0);
    k_parts<<<2048, 256, 0, stream>>>(img, parts_bf);

    k_scan<<<256, 512, 0, stream>>>(xh, c0, parts_bf, Wsmall, Wbig, Ww2, bias,
                                    Ub, betab, Wb, vw, label, ow, ob,
                                    out_alpha, out_logits, flags);
}